// Round 1
// baseline (3106.950 us; speedup 1.0000x reference)
//
#include <hip/hip_runtime.h>
#include <hip/hip_bf16.h>
#include <math.h>

// ---------------------------------------------------------------------------
// NetNode: 3x (GraphConv -> TopKPooling -> readout) + FC/BN head + per-node dot
// B=256 graphs, N=512 nodes, E=2048 edges per graph, feature dim 128, EMB=64.
// All fp32. k1=461, k2=415, k3=374.
// ---------------------------------------------------------------------------

#define TOTAL_NODES 131072   // B*N
#define NUM_GRAPHS  256
#define NODES_PER_G 512
#define E_TOTAL     524288   // B*E
#define FDIM        128
#define EMBD        64

static inline size_t align256(size_t x) { return (x + 255) & ~size_t(255); }

// ---------------- gather embeddings: x[:,0:64]=emb_item[item], x[:,64:128]=emb_cat[cat]
__global__ __launch_bounds__(256) void gather_embed_k(
    const int* __restrict__ item_id, const int* __restrict__ cat_id,
    const float* __restrict__ emb_item, const float* __restrict__ emb_cat,
    float* __restrict__ x, int total)
{
  int i = blockIdx.x * 256 + threadIdx.x;
  int node = i >> 5, part = i & 31;          // 32 float4 per 128-f row
  if (node >= total) return;
  float4 v;
  if (part < 16) {
    v = *(const float4*)&emb_item[(size_t)item_id[node] * EMBD + part * 4];
  } else {
    v = *(const float4*)&emb_cat[(size_t)cat_id[node] * EMBD + (part - 16) * 4];
  }
  *(float4*)&x[(size_t)node * FDIM + part * 4] = v;
}

// ---------------- scatter-add messages: agg[dst] += x[src] (invalid edges src/dst = -1)
__global__ __launch_bounds__(256) void scatter_add_k(
    const float* __restrict__ x, const int* __restrict__ src,
    const int* __restrict__ dst, float* __restrict__ agg, int E)
{
  int i = blockIdx.x * 256 + threadIdx.x;
  int e = i >> 5, part = i & 31;
  if (e >= E) return;
  int s = src[e];
  if (s < 0) return;
  int d = dst[e];
  if (d < 0) return;
  float4 v = *(const float4*)&x[(size_t)s * FDIM + part * 4];
  float* o = &agg[(size_t)d * FDIM + part * 4];
  unsafeAtomicAdd(o + 0, v.x);
  unsafeAtomicAdd(o + 1, v.y);
  unsafeAtomicAdd(o + 2, v.z);
  unsafeAtomicAdd(o + 3, v.w);
}

// ---------------- C[M,128] = relu(A1@W1 + A2@W2 + b). M multiple of 128.
// Block: 256 threads, 128x128 tile, 8x8 per thread. In-place safe (C may == A1).
__global__ __launch_bounds__(256) void conv_gemm_k(
    const float* __restrict__ A1, const float* __restrict__ W1,
    const float* __restrict__ A2, const float* __restrict__ W2,
    const float* __restrict__ bias, float* __restrict__ C, int M)
{
  __shared__ float As[128][17];
  __shared__ float Ws[16][129];
  const int tid = threadIdx.x;
  const int tx = tid & 15, ty = tid >> 4;
  const int row0 = blockIdx.x * 128;

  float acc[8][8];
#pragma unroll
  for (int r = 0; r < 8; ++r)
#pragma unroll
    for (int c = 0; c < 8; ++c) acc[r][c] = 0.f;

  for (int pass = 0; pass < 2; ++pass) {
    const float* __restrict__ A = pass ? A2 : A1;
    const float* __restrict__ W = pass ? W2 : W1;
    for (int k0 = 0; k0 < 128; k0 += 16) {
      // load A tile 128x16 (512 float4, 2 per thread)
#pragma unroll
      for (int q = 0; q < 2; ++q) {
        int v = q * 256 + tid;
        int ar = v >> 2, ac = (v & 3) * 4;
        float4 t = *(const float4*)&A[(size_t)(row0 + ar) * FDIM + k0 + ac];
        As[ar][ac + 0] = t.x; As[ar][ac + 1] = t.y;
        As[ar][ac + 2] = t.z; As[ar][ac + 3] = t.w;
      }
      // load W tile 16x128
#pragma unroll
      for (int q = 0; q < 2; ++q) {
        int v = q * 256 + tid;
        int wr = v >> 5, wc = (v & 31) * 4;
        float4 t = *(const float4*)&W[(size_t)(k0 + wr) * FDIM + wc];
        Ws[wr][wc + 0] = t.x; Ws[wr][wc + 1] = t.y;
        Ws[wr][wc + 2] = t.z; Ws[wr][wc + 3] = t.w;
      }
      __syncthreads();
#pragma unroll
      for (int kk = 0; kk < 16; ++kk) {
        float a[8], w[8];
#pragma unroll
        for (int r = 0; r < 8; ++r) a[r] = As[ty + r * 16][kk];
#pragma unroll
        for (int c = 0; c < 8; ++c) w[c] = Ws[kk][tx + c * 16];
#pragma unroll
        for (int r = 0; r < 8; ++r)
#pragma unroll
          for (int c = 0; c < 8; ++c) acc[r][c] += a[r] * w[c];
      }
      __syncthreads();
    }
  }
#pragma unroll
  for (int r = 0; r < 8; ++r) {
    int row = row0 + ty + r * 16;
#pragma unroll
    for (int c = 0; c < 8; ++c) {
      int col = tx + c * 16;
      float v = acc[r][c] + bias[col];
      C[(size_t)row * FDIM + col] = fmaxf(v, 0.f);
    }
  }
}

// ---------------- ||p|| (p has 128 elems), single block 128 threads
__global__ __launch_bounds__(128) void pnorm_k(const float* __restrict__ p,
                                               float* __restrict__ nrm)
{
  __shared__ float ss[128];
  int t = threadIdx.x;
  float v = p[t];
  ss[t] = v * v;
  __syncthreads();
  for (int s = 64; s > 0; s >>= 1) {
    if (t < s) ss[t] += ss[t + s];
    __syncthreads();
  }
  if (t == 0) nrm[0] = sqrtf(ss[0]);
}

// ---------------- score[i] = dot(x[i], p) / ||p||
__global__ __launch_bounds__(256) void score_k(
    const float* __restrict__ x, const float* __restrict__ p,
    const float* __restrict__ nrm, float* __restrict__ score, int M)
{
  int i = blockIdx.x * 256 + threadIdx.x;
  if (i >= M) return;
  float n = nrm[0];
  float s = 0.f;
  const float* row = &x[(size_t)i * FDIM];
#pragma unroll
  for (int j = 0; j < FDIM; j += 4) {
    float4 xv = *(const float4*)&row[j];
    float4 pv = *(const float4*)&p[j];
    s += xv.x * pv.x + xv.y * pv.y + xv.z * pv.z + xv.w * pv.w;
  }
  score[i] = s / n;
}

// ---------------- per-graph top-k via bitonic sort of (key=-score, idx), 512 wide
__global__ __launch_bounds__(512) void topk_sort_k(
    const float* __restrict__ score, int n_old, int k_new,
    int* __restrict__ sel, int* __restrict__ mapping)
{
  __shared__ float sv[512];
  __shared__ int   si[512];
  int b = blockIdx.x, t = threadIdx.x;
  sv[t] = (t < n_old) ? -score[(size_t)b * n_old + t] : 3.0e38f;
  si[t] = t;
  __syncthreads();
  for (int k = 2; k <= 512; k <<= 1) {
    for (int j = k >> 1; j > 0; j >>= 1) {
      int ixj = t ^ j;
      if (ixj > t) {
        bool up = ((t & k) == 0);
        float a = sv[t], c = sv[ixj];
        if ((a > c) == up) {
          sv[t] = c; sv[ixj] = a;
          int tmp = si[t]; si[t] = si[ixj]; si[ixj] = tmp;
        }
      }
      __syncthreads();
    }
  }
  // ascending in -score -> position 0 has the largest score
  if (t < n_old) {
    int old_g = b * n_old + si[t];
    if (t < k_new) {
      sel[b * k_new + t] = old_g;
      mapping[old_g] = b * k_new + t;
    } else {
      mapping[old_g] = -1;
    }
  }
}

// ---------------- pooled gather with tanh(score) gate
__global__ __launch_bounds__(256) void pool_gather_k(
    const float* __restrict__ x, const float* __restrict__ score,
    const int* __restrict__ sel, float* __restrict__ xout, int Mnew)
{
  int i = blockIdx.x * 256 + threadIdx.x;
  int node = i >> 5, part = i & 31;
  if (node >= Mnew) return;
  int old = sel[node];
  float g = tanhf(score[old]);
  float4 v = *(const float4*)&x[(size_t)old * FDIM + part * 4];
  v.x *= g; v.y *= g; v.z *= g; v.w *= g;
  *(float4*)&xout[(size_t)node * FDIM + part * 4] = v;
}

// ---------------- edge remap through mapping; invalid -> -1 (in-place safe)
__global__ __launch_bounds__(256) void edge_remap_k(
    const int* __restrict__ src_in, const int* __restrict__ dst_in,
    const int* __restrict__ mapping, int* __restrict__ src_out,
    int* __restrict__ dst_out, int E)
{
  int e = blockIdx.x * 256 + threadIdx.x;
  if (e >= E) return;
  int s = src_in[e], d = dst_in[e];
  int ns = (s >= 0) ? mapping[s] : -1;
  int nd = (d >= 0) ? mapping[d] : -1;
  if (ns < 0 || nd < 0) { ns = -1; nd = -1; }
  src_out[e] = ns;
  dst_out[e] = nd;
}

// ---------------- readout: g[b, 0:128] += max over k rows, g[b,128:256] += mean
__global__ __launch_bounds__(128) void readout_k(
    const float* __restrict__ x, int k, float* __restrict__ g)
{
  int b = blockIdx.x, c = threadIdx.x;   // 128 threads = feature cols
  const float* base = x + (size_t)b * k * FDIM + c;
  float mx = -3.0e38f, sm = 0.f;
  for (int r = 0; r < k; ++r) {
    float v = base[(size_t)r * FDIM];
    mx = fmaxf(mx, v);
    sm += v;
  }
  g[b * 256 + c]       += mx;
  g[b * 256 + 128 + c] += sm / (float)k;
}

// ---------------- fc: h[rows, C] = g[rows, K] @ W[K, C] + b
__global__ __launch_bounds__(256) void fc_k(
    const float* __restrict__ in, const float* __restrict__ W,
    const float* __restrict__ bias, float* __restrict__ out,
    int rows, int K, int C)
{
  int idx = blockIdx.x * 256 + threadIdx.x;
  if (idx >= rows * C) return;
  int row = idx / C, c = idx % C;
  float s = bias[c];
  const float* grow = &in[(size_t)row * K];
  for (int t = 0; t < K; ++t) s += grow[t] * W[(size_t)t * C + c];
  out[idx] = s;
}

// ---------------- BatchNorm (training stats over 256 rows) + relu, in place
__global__ __launch_bounds__(256) void bn_relu_k(
    float* __restrict__ h, const float* __restrict__ gamma,
    const float* __restrict__ beta, int C)
{
  __shared__ float ssum[256], ssq[256];
  int c = blockIdx.x, r = threadIdx.x;   // 256 rows
  float v = h[(size_t)r * C + c];
  ssum[r] = v; ssq[r] = v * v;
  __syncthreads();
  for (int s = 128; s > 0; s >>= 1) {
    if (r < s) { ssum[r] += ssum[r + s]; ssq[r] += ssq[r + s]; }
    __syncthreads();
  }
  float m = ssum[0] * (1.f / 256.f);
  float var = ssq[0] * (1.f / 256.f) - m * m;
  float o = gamma[c] * (v - m) * rsqrtf(var + 1e-5f) + beta[c];
  h[(size_t)r * C + c] = fmaxf(o, 0.f);
}

// ---------------- out[nid] = sigmoid(dot(emb_item[item_id[nid]], g2[graph]))
__global__ __launch_bounds__(256) void final_k(
    const int* __restrict__ item_id, const float* __restrict__ emb_item,
    const float* __restrict__ g2, float* __restrict__ out, int total)
{
  int nid = blockIdx.x * 256 + threadIdx.x;
  if (nid >= total) return;
  int b = nid >> 9;  // 512 nodes per graph
  const float* e = &emb_item[(size_t)item_id[nid] * EMBD];
  const float* gg = &g2[(size_t)b * 64];
  float s = 0.f;
#pragma unroll
  for (int j = 0; j < 64; j += 4) {
    float4 a = *(const float4*)&e[j];
    float4 c = *(const float4*)&gg[j];
    s += a.x * c.x + a.y * c.y + a.z * c.z + a.w * c.w;
  }
  out[nid] = 1.f / (1.f + expf(-s));
}

// ---------------------------------------------------------------------------
extern "C" void kernel_launch(void* const* d_in, const int* in_sizes, int n_in,
                              void* d_out, int out_size, void* d_ws, size_t ws_size,
                              hipStream_t stream)
{
  // inputs per setup_inputs() order
  const int*   item_id  = (const int*)  d_in[0];
  const int*   cat_id   = (const int*)  d_in[1];
  const int*   src_in   = (const int*)  d_in[2];
  const int*   dst_in   = (const int*)  d_in[3];
  const float* emb_item = (const float*)d_in[4];
  const float* emb_cat  = (const float*)d_in[5];
  const float* W1r = (const float*)d_in[6];
  const float* W1n = (const float*)d_in[7];
  const float* b1  = (const float*)d_in[8];
  const float* p1  = (const float*)d_in[9];
  const float* W2r = (const float*)d_in[10];
  const float* W2n = (const float*)d_in[11];
  const float* b2  = (const float*)d_in[12];
  const float* p2  = (const float*)d_in[13];
  const float* W3r = (const float*)d_in[14];
  const float* W3n = (const float*)d_in[15];
  const float* b3  = (const float*)d_in[16];
  const float* p3  = (const float*)d_in[17];
  const float* fc1_W = (const float*)d_in[18];
  const float* fc1_b = (const float*)d_in[19];
  const float* bn1_g = (const float*)d_in[20];
  const float* bn1_b = (const float*)d_in[21];
  const float* fc2_W = (const float*)d_in[22];
  const float* fc2_b = (const float*)d_in[23];
  const float* bn2_g = (const float*)d_in[24];
  const float* bn2_b = (const float*)d_in[25];
  float* out = (float*)d_out;

  const int TN = TOTAL_NODES;     // 131072
  const int E  = E_TOTAL;         // 524288
  const int k1 = 461, k2 = 415, k3 = 374;
  const int M1 = TN;                      // 131072
  const int M2 = NUM_GRAPHS * k1;         // 118016
  const int M3 = NUM_GRAPHS * k2;         // 106240
  const int M4 = NUM_GRAPHS * k3;         // 95744

  // workspace carve-up
  char* ws = (char*)d_ws;
  size_t off = 0;
  auto carve = [&](size_t bytes) { char* p = ws + off; off += align256(bytes); return p; };
  float* buf0   = (float*)carve((size_t)TN * FDIM * 4);   // 64 MB
  float* buf1   = (float*)carve((size_t)TN * FDIM * 4);   // 64 MB
  float* score  = (float*)carve((size_t)TN * 4);
  int*   sel    = (int*)  carve((size_t)TN * 4);
  int*   mapping= (int*)  carve((size_t)TN * 4);
  int*   srcw   = (int*)  carve((size_t)E * 4);
  int*   dstw   = (int*)  carve((size_t)E * 4);
  float* g      = (float*)carve(256 * 256 * 4);
  float* h1     = (float*)carve(256 * 128 * 4);
  float* h2     = (float*)carve(256 * 64 * 4);
  float* nrm    = (float*)carve(256);
  if (off > ws_size) return;  // insufficient workspace -> fail loudly in validation

  dim3 b256(256);
  auto blocks = [](long long work, int bs) { return dim3((unsigned)((work + bs - 1) / bs)); };

  // ---- init
  hipMemsetAsync(g, 0, 256 * 256 * 4, stream);

  // ---- stage 0: gather embeddings -> buf0
  gather_embed_k<<<blocks((long long)TN * 32, 256), b256, 0, stream>>>(
      item_id, cat_id, emb_item, emb_cat, buf0, TN);

  // ================= stage 1 =================
  hipMemsetAsync(buf1, 0, (size_t)M1 * FDIM * 4, stream);
  scatter_add_k<<<blocks((long long)E * 32, 256), b256, 0, stream>>>(
      buf0, src_in, dst_in, buf1, E);
  conv_gemm_k<<<dim3(M1 / 128), b256, 0, stream>>>(buf0, W1r, buf1, W1n, b1, buf0, M1);
  pnorm_k<<<dim3(1), dim3(128), 0, stream>>>(p1, nrm);
  score_k<<<blocks(M1, 256), b256, 0, stream>>>(buf0, p1, nrm, score, M1);
  topk_sort_k<<<dim3(NUM_GRAPHS), dim3(512), 0, stream>>>(score, NODES_PER_G, k1, sel, mapping);
  pool_gather_k<<<blocks((long long)M2 * 32, 256), b256, 0, stream>>>(buf0, score, sel, buf1, M2);
  edge_remap_k<<<blocks(E, 256), b256, 0, stream>>>(src_in, dst_in, mapping, srcw, dstw, E);
  readout_k<<<dim3(NUM_GRAPHS), dim3(128), 0, stream>>>(buf1, k1, g);

  // ================= stage 2 (x = buf1) =================
  hipMemsetAsync(buf0, 0, (size_t)M2 * FDIM * 4, stream);
  scatter_add_k<<<blocks((long long)E * 32, 256), b256, 0, stream>>>(
      buf1, srcw, dstw, buf0, E);
  conv_gemm_k<<<dim3(M2 / 128), b256, 0, stream>>>(buf1, W2r, buf0, W2n, b2, buf1, M2);
  pnorm_k<<<dim3(1), dim3(128), 0, stream>>>(p2, nrm);
  score_k<<<blocks(M2, 256), b256, 0, stream>>>(buf1, p2, nrm, score, M2);
  topk_sort_k<<<dim3(NUM_GRAPHS), dim3(512), 0, stream>>>(score, k1, k2, sel, mapping);
  pool_gather_k<<<blocks((long long)M3 * 32, 256), b256, 0, stream>>>(buf1, score, sel, buf0, M3);
  edge_remap_k<<<blocks(E, 256), b256, 0, stream>>>(srcw, dstw, mapping, srcw, dstw, E);
  readout_k<<<dim3(NUM_GRAPHS), dim3(128), 0, stream>>>(buf0, k2, g);

  // ================= stage 3 (x = buf0) =================
  hipMemsetAsync(buf1, 0, (size_t)M3 * FDIM * 4, stream);
  scatter_add_k<<<blocks((long long)E * 32, 256), b256, 0, stream>>>(
      buf0, srcw, dstw, buf1, E);
  conv_gemm_k<<<dim3(M3 / 128), b256, 0, stream>>>(buf0, W3r, buf1, W3n, b3, buf0, M3);
  pnorm_k<<<dim3(1), dim3(128), 0, stream>>>(p3, nrm);
  score_k<<<blocks(M3, 256), b256, 0, stream>>>(buf0, p3, nrm, score, M3);
  topk_sort_k<<<dim3(NUM_GRAPHS), dim3(512), 0, stream>>>(score, k2, k3, sel, mapping);
  pool_gather_k<<<blocks((long long)M4 * 32, 256), b256, 0, stream>>>(buf0, score, sel, buf1, M4);
  readout_k<<<dim3(NUM_GRAPHS), dim3(128), 0, stream>>>(buf1, k3, g);

  // ================= head =================
  fc_k<<<blocks(256 * 128, 256), b256, 0, stream>>>(g, fc1_W, fc1_b, h1, 256, 256, 128);
  bn_relu_k<<<dim3(128), b256, 0, stream>>>(h1, bn1_g, bn1_b, 128);
  fc_k<<<blocks(256 * 64, 256), b256, 0, stream>>>(h1, fc2_W, fc2_b, h2, 256, 128, 64);
  bn_relu_k<<<dim3(64), b256, 0, stream>>>(h2, bn2_g, bn2_b, 64);

  // ================= final per-node sigmoid dot =================
  final_k<<<blocks(TN, 256), b256, 0, stream>>>(item_id, emb_item, h2, out, TN);
}

// Round 2
// 1121.135 us; speedup vs baseline: 2.7713x; 2.7713x over previous
//
#include <hip/hip_runtime.h>
#include <hip/hip_bf16.h>
#include <math.h>

// ---------------------------------------------------------------------------
// NetNode: 3x (GraphConv -> TopKPooling -> readout) + FC/BN head + per-node dot
// B=256 graphs, N=512 nodes, E=2048 edges per graph, feature dim 128, EMB=64.
// All fp32. k1=461, k2=415, k3=374.
// R2: scatter-add (global f32 atomics, 884us each) replaced by CSR build +
//     register-accumulated gather (atomic-free heavy path).
// ---------------------------------------------------------------------------

#define TOTAL_NODES 131072   // B*N
#define NUM_GRAPHS  256
#define NODES_PER_G 512
#define E_TOTAL     524288   // B*E
#define EPG         2048     // edges per graph (slot capacity)
#define FDIM        128
#define EMBD        64

static inline size_t align256(size_t x) { return (x + 255) & ~size_t(255); }

// ---------------- gather embeddings: x[:,0:64]=emb_item[item], x[:,64:128]=emb_cat[cat]
__global__ __launch_bounds__(256) void gather_embed_k(
    const int* __restrict__ item_id, const int* __restrict__ cat_id,
    const float* __restrict__ emb_item, const float* __restrict__ emb_cat,
    float* __restrict__ x, int total)
{
  int i = blockIdx.x * 256 + threadIdx.x;
  int node = i >> 5, part = i & 31;          // 32 float4 per 128-f row
  if (node >= total) return;
  float4 v;
  if (part < 16) {
    v = *(const float4*)&emb_item[(size_t)item_id[node] * EMBD + part * 4];
  } else {
    v = *(const float4*)&emb_cat[(size_t)cat_id[node] * EMBD + (part - 16) * 4];
  }
  *(float4*)&x[(size_t)node * FDIM + part * 4] = v;
}

// ================= CSR build =================
// counts must be zeroed first (memsetAsync). Valid edges have src>=0 && dst>=0
// (remap sets both to -1 together).
__global__ __launch_bounds__(256) void csr_count_k(
    const int* __restrict__ dst, int* __restrict__ counts, int E)
{
  int e = blockIdx.x * 256 + threadIdx.x;
  if (e >= E) return;
  int d = dst[e];
  if (d < 0) return;
  atomicAdd(&counts[d], 1);
}

// one block per graph: exclusive scan of per-node counts -> absolute slot offsets
__global__ __launch_bounds__(512) void csr_scan_k(
    const int* __restrict__ counts, int n, int* __restrict__ off,
    int* __restrict__ cursor)
{
  __shared__ int s[512];
  int g = blockIdx.x, t = threadIdx.x;
  int v = (t < n) ? counts[g * n + t] : 0;
  s[t] = v;
  __syncthreads();
  for (int d = 1; d < 512; d <<= 1) {
    int add = (t >= d) ? s[t - d] : 0;
    __syncthreads();
    s[t] += add;
    __syncthreads();
  }
  if (t < n) {
    int abs_off = g * EPG + (s[t] - v);   // exclusive prefix
    off[g * n + t] = abs_off;
    cursor[g * n + t] = abs_off;
  }
}

__global__ __launch_bounds__(256) void csr_scatter_k(
    const int* __restrict__ src, const int* __restrict__ dst,
    int* __restrict__ cursor, int* __restrict__ slots, int E)
{
  int e = blockIdx.x * 256 + threadIdx.x;
  if (e >= E) return;
  int d = dst[e];
  if (d < 0) return;
  int pos = atomicAdd(&cursor[d], 1);
  slots[pos] = src[e];
}

// ---------------- atomic-free aggregation: agg[i] = sum_{e: dst=i} x[src_e]
// 32 lanes per node, float4 per lane. Writes ALL M rows (zero for deg 0).
__global__ __launch_bounds__(256) void gather_agg_k(
    const float* __restrict__ x, const int* __restrict__ slots,
    const int* __restrict__ off, const int* __restrict__ counts,
    float* __restrict__ agg, int M)
{
  int i = blockIdx.x * 256 + threadIdx.x;
  int node = i >> 5, lane = i & 31;
  if (node >= M) return;
  int deg = counts[node];
  int base = off[node];
  float4 acc = make_float4(0.f, 0.f, 0.f, 0.f);
  for (int d = 0; d < deg; ++d) {
    int s = slots[base + d];
    float4 v = *(const float4*)&x[(size_t)s * FDIM + lane * 4];
    acc.x += v.x; acc.y += v.y; acc.z += v.z; acc.w += v.w;
  }
  *(float4*)&agg[(size_t)node * FDIM + lane * 4] = acc;
}

// ---------------- C[M,128] = relu(A1@W1 + A2@W2 + b). M multiple of 128.
// Block: 256 threads, 128x128 tile, 8x8 per thread. In-place safe (C may == A1).
__global__ __launch_bounds__(256) void conv_gemm_k(
    const float* __restrict__ A1, const float* __restrict__ W1,
    const float* __restrict__ A2, const float* __restrict__ W2,
    const float* __restrict__ bias, float* __restrict__ C, int M)
{
  __shared__ float As[128][17];
  __shared__ float Ws[16][129];
  const int tid = threadIdx.x;
  const int tx = tid & 15, ty = tid >> 4;
  const int row0 = blockIdx.x * 128;

  float acc[8][8];
#pragma unroll
  for (int r = 0; r < 8; ++r)
#pragma unroll
    for (int c = 0; c < 8; ++c) acc[r][c] = 0.f;

  for (int pass = 0; pass < 2; ++pass) {
    const float* __restrict__ A = pass ? A2 : A1;
    const float* __restrict__ W = pass ? W2 : W1;
    for (int k0 = 0; k0 < 128; k0 += 16) {
#pragma unroll
      for (int q = 0; q < 2; ++q) {
        int v = q * 256 + tid;
        int ar = v >> 2, ac = (v & 3) * 4;
        float4 t = *(const float4*)&A[(size_t)(row0 + ar) * FDIM + k0 + ac];
        As[ar][ac + 0] = t.x; As[ar][ac + 1] = t.y;
        As[ar][ac + 2] = t.z; As[ar][ac + 3] = t.w;
      }
#pragma unroll
      for (int q = 0; q < 2; ++q) {
        int v = q * 256 + tid;
        int wr = v >> 5, wc = (v & 31) * 4;
        float4 t = *(const float4*)&W[(size_t)(k0 + wr) * FDIM + wc];
        Ws[wr][wc + 0] = t.x; Ws[wr][wc + 1] = t.y;
        Ws[wr][wc + 2] = t.z; Ws[wr][wc + 3] = t.w;
      }
      __syncthreads();
#pragma unroll
      for (int kk = 0; kk < 16; ++kk) {
        float a[8], w[8];
#pragma unroll
        for (int r = 0; r < 8; ++r) a[r] = As[ty + r * 16][kk];
#pragma unroll
        for (int c = 0; c < 8; ++c) w[c] = Ws[kk][tx + c * 16];
#pragma unroll
        for (int r = 0; r < 8; ++r)
#pragma unroll
          for (int c = 0; c < 8; ++c) acc[r][c] += a[r] * w[c];
      }
      __syncthreads();
    }
  }
#pragma unroll
  for (int r = 0; r < 8; ++r) {
    int row = row0 + ty + r * 16;
#pragma unroll
    for (int c = 0; c < 8; ++c) {
      int col = tx + c * 16;
      float v = acc[r][c] + bias[col];
      C[(size_t)row * FDIM + col] = fmaxf(v, 0.f);
    }
  }
}

// ---------------- ||p|| (p has 128 elems), single block 128 threads
__global__ __launch_bounds__(128) void pnorm_k(const float* __restrict__ p,
                                               float* __restrict__ nrm)
{
  __shared__ float ss[128];
  int t = threadIdx.x;
  float v = p[t];
  ss[t] = v * v;
  __syncthreads();
  for (int s = 64; s > 0; s >>= 1) {
    if (t < s) ss[t] += ss[t + s];
    __syncthreads();
  }
  if (t == 0) nrm[0] = sqrtf(ss[0]);
}

// ---------------- score[i] = dot(x[i], p) / ||p||
__global__ __launch_bounds__(256) void score_k(
    const float* __restrict__ x, const float* __restrict__ p,
    const float* __restrict__ nrm, float* __restrict__ score, int M)
{
  int i = blockIdx.x * 256 + threadIdx.x;
  if (i >= M) return;
  float n = nrm[0];
  float s = 0.f;
  const float* row = &x[(size_t)i * FDIM];
#pragma unroll
  for (int j = 0; j < FDIM; j += 4) {
    float4 xv = *(const float4*)&row[j];
    float4 pv = *(const float4*)&p[j];
    s += xv.x * pv.x + xv.y * pv.y + xv.z * pv.z + xv.w * pv.w;
  }
  score[i] = s / n;
}

// ---------------- per-graph top-k via bitonic sort of (key=-score, idx), 512 wide
__global__ __launch_bounds__(512) void topk_sort_k(
    const float* __restrict__ score, int n_old, int k_new,
    int* __restrict__ sel, int* __restrict__ mapping)
{
  __shared__ float sv[512];
  __shared__ int   si[512];
  int b = blockIdx.x, t = threadIdx.x;
  sv[t] = (t < n_old) ? -score[(size_t)b * n_old + t] : 3.0e38f;
  si[t] = t;
  __syncthreads();
  for (int k = 2; k <= 512; k <<= 1) {
    for (int j = k >> 1; j > 0; j >>= 1) {
      int ixj = t ^ j;
      if (ixj > t) {
        bool up = ((t & k) == 0);
        float a = sv[t], c = sv[ixj];
        if ((a > c) == up) {
          sv[t] = c; sv[ixj] = a;
          int tmp = si[t]; si[t] = si[ixj]; si[ixj] = tmp;
        }
      }
      __syncthreads();
    }
  }
  if (t < n_old) {
    int old_g = b * n_old + si[t];
    if (t < k_new) {
      sel[b * k_new + t] = old_g;
      mapping[old_g] = b * k_new + t;
    } else {
      mapping[old_g] = -1;
    }
  }
}

// ---------------- pooled gather with tanh(score) gate
__global__ __launch_bounds__(256) void pool_gather_k(
    const float* __restrict__ x, const float* __restrict__ score,
    const int* __restrict__ sel, float* __restrict__ xout, int Mnew)
{
  int i = blockIdx.x * 256 + threadIdx.x;
  int node = i >> 5, part = i & 31;
  if (node >= Mnew) return;
  int old = sel[node];
  float g = tanhf(score[old]);
  float4 v = *(const float4*)&x[(size_t)old * FDIM + part * 4];
  v.x *= g; v.y *= g; v.z *= g; v.w *= g;
  *(float4*)&xout[(size_t)node * FDIM + part * 4] = v;
}

// ---------------- edge remap through mapping; invalid -> -1 (in-place safe)
__global__ __launch_bounds__(256) void edge_remap_k(
    const int* __restrict__ src_in, const int* __restrict__ dst_in,
    const int* __restrict__ mapping, int* __restrict__ src_out,
    int* __restrict__ dst_out, int E)
{
  int e = blockIdx.x * 256 + threadIdx.x;
  if (e >= E) return;
  int s = src_in[e], d = dst_in[e];
  int ns = (s >= 0) ? mapping[s] : -1;
  int nd = (d >= 0) ? mapping[d] : -1;
  if (ns < 0 || nd < 0) { ns = -1; nd = -1; }
  src_out[e] = ns;
  dst_out[e] = nd;
}

// ---------------- readout: g[b, 0:128] += max over k rows, g[b,128:256] += mean
__global__ __launch_bounds__(128) void readout_k(
    const float* __restrict__ x, int k, float* __restrict__ g)
{
  int b = blockIdx.x, c = threadIdx.x;   // 128 threads = feature cols
  const float* base = x + (size_t)b * k * FDIM + c;
  float mx = -3.0e38f, sm = 0.f;
  for (int r = 0; r < k; ++r) {
    float v = base[(size_t)r * FDIM];
    mx = fmaxf(mx, v);
    sm += v;
  }
  g[b * 256 + c]       += mx;
  g[b * 256 + 128 + c] += sm / (float)k;
}

// ---------------- fc: h[rows, C] = g[rows, K] @ W[K, C] + b
__global__ __launch_bounds__(256) void fc_k(
    const float* __restrict__ in, const float* __restrict__ W,
    const float* __restrict__ bias, float* __restrict__ out,
    int rows, int K, int C)
{
  int idx = blockIdx.x * 256 + threadIdx.x;
  if (idx >= rows * C) return;
  int row = idx / C, c = idx % C;
  float s = bias[c];
  const float* grow = &in[(size_t)row * K];
  for (int t = 0; t < K; ++t) s += grow[t] * W[(size_t)t * C + c];
  out[idx] = s;
}

// ---------------- BatchNorm (training stats over 256 rows) + relu, in place
__global__ __launch_bounds__(256) void bn_relu_k(
    float* __restrict__ h, const float* __restrict__ gamma,
    const float* __restrict__ beta, int C)
{
  __shared__ float ssum[256], ssq[256];
  int c = blockIdx.x, r = threadIdx.x;   // 256 rows
  float v = h[(size_t)r * C + c];
  ssum[r] = v; ssq[r] = v * v;
  __syncthreads();
  for (int s = 128; s > 0; s >>= 1) {
    if (r < s) { ssum[r] += ssum[r + s]; ssq[r] += ssq[r + s]; }
    __syncthreads();
  }
  float m = ssum[0] * (1.f / 256.f);
  float var = ssq[0] * (1.f / 256.f) - m * m;
  float o = gamma[c] * (v - m) * rsqrtf(var + 1e-5f) + beta[c];
  h[(size_t)r * C + c] = fmaxf(o, 0.f);
}

// ---------------- out[nid] = sigmoid(dot(emb_item[item_id[nid]], g2[graph]))
__global__ __launch_bounds__(256) void final_k(
    const int* __restrict__ item_id, const float* __restrict__ emb_item,
    const float* __restrict__ g2, float* __restrict__ out, int total)
{
  int nid = blockIdx.x * 256 + threadIdx.x;
  if (nid >= total) return;
  int b = nid >> 9;  // 512 nodes per graph
  const float* e = &emb_item[(size_t)item_id[nid] * EMBD];
  const float* gg = &g2[(size_t)b * 64];
  float s = 0.f;
#pragma unroll
  for (int j = 0; j < 64; j += 4) {
    float4 a = *(const float4*)&e[j];
    float4 c = *(const float4*)&gg[j];
    s += a.x * c.x + a.y * c.y + a.z * c.z + a.w * c.w;
  }
  out[nid] = 1.f / (1.f + expf(-s));
}

// ---------------------------------------------------------------------------
extern "C" void kernel_launch(void* const* d_in, const int* in_sizes, int n_in,
                              void* d_out, int out_size, void* d_ws, size_t ws_size,
                              hipStream_t stream)
{
  const int*   item_id  = (const int*)  d_in[0];
  const int*   cat_id   = (const int*)  d_in[1];
  const int*   src_in   = (const int*)  d_in[2];
  const int*   dst_in   = (const int*)  d_in[3];
  const float* emb_item = (const float*)d_in[4];
  const float* emb_cat  = (const float*)d_in[5];
  const float* W1r = (const float*)d_in[6];
  const float* W1n = (const float*)d_in[7];
  const float* b1  = (const float*)d_in[8];
  const float* p1  = (const float*)d_in[9];
  const float* W2r = (const float*)d_in[10];
  const float* W2n = (const float*)d_in[11];
  const float* b2  = (const float*)d_in[12];
  const float* p2  = (const float*)d_in[13];
  const float* W3r = (const float*)d_in[14];
  const float* W3n = (const float*)d_in[15];
  const float* b3  = (const float*)d_in[16];
  const float* p3  = (const float*)d_in[17];
  const float* fc1_W = (const float*)d_in[18];
  const float* fc1_b = (const float*)d_in[19];
  const float* bn1_g = (const float*)d_in[20];
  const float* bn1_b = (const float*)d_in[21];
  const float* fc2_W = (const float*)d_in[22];
  const float* fc2_b = (const float*)d_in[23];
  const float* bn2_g = (const float*)d_in[24];
  const float* bn2_b = (const float*)d_in[25];
  float* out = (float*)d_out;

  const int TN = TOTAL_NODES;     // 131072
  const int E  = E_TOTAL;         // 524288
  const int k1 = 461, k2 = 415, k3 = 374;
  const int M1 = TN;                      // 131072
  const int M2 = NUM_GRAPHS * k1;         // 118016
  const int M3 = NUM_GRAPHS * k2;         // 106240
  const int M4 = NUM_GRAPHS * k3;         // 95744

  // workspace carve-up
  char* ws = (char*)d_ws;
  size_t off = 0;
  auto carve = [&](size_t bytes) { char* p = ws + off; off += align256(bytes); return p; };
  float* buf0   = (float*)carve((size_t)TN * FDIM * 4);   // 64 MB
  float* buf1   = (float*)carve((size_t)TN * FDIM * 4);   // 64 MB
  float* score  = (float*)carve((size_t)TN * 4);
  int*   sel    = (int*)  carve((size_t)TN * 4);
  int*   mapping= (int*)  carve((size_t)TN * 4);
  int*   srcw   = (int*)  carve((size_t)E * 4);
  int*   dstw   = (int*)  carve((size_t)E * 4);
  int*   counts = (int*)  carve((size_t)TN * 4);
  int*   offs   = (int*)  carve((size_t)TN * 4);
  int*   cursor = (int*)  carve((size_t)TN * 4);
  int*   slots  = (int*)  carve((size_t)E * 4);
  float* g      = (float*)carve(256 * 256 * 4);
  float* h1     = (float*)carve(256 * 128 * 4);
  float* h2     = (float*)carve(256 * 64 * 4);
  float* nrm    = (float*)carve(256);
  if (off > ws_size) return;

  dim3 b256(256);
  auto blocks = [](long long work, int bs) { return dim3((unsigned)((work + bs - 1) / bs)); };

  // helper to run one aggregation: agg[i] = sum_{e: dst=i} x[src]
  auto aggregate = [&](const float* x, const int* s, const int* d, float* agg,
                       int n_per_g, int M) {
    hipMemsetAsync(counts, 0, (size_t)M * 4, stream);
    csr_count_k<<<blocks(E, 256), b256, 0, stream>>>(d, counts, E);
    csr_scan_k<<<dim3(NUM_GRAPHS), dim3(512), 0, stream>>>(counts, n_per_g, offs, cursor);
    csr_scatter_k<<<blocks(E, 256), b256, 0, stream>>>(s, d, cursor, slots, E);
    gather_agg_k<<<blocks((long long)M * 32, 256), b256, 0, stream>>>(
        x, slots, offs, counts, agg, M);
  };

  // ---- init
  hipMemsetAsync(g, 0, 256 * 256 * 4, stream);

  // ---- stage 0: gather embeddings -> buf0
  gather_embed_k<<<blocks((long long)TN * 32, 256), b256, 0, stream>>>(
      item_id, cat_id, emb_item, emb_cat, buf0, TN);

  // ================= stage 1 =================
  aggregate(buf0, src_in, dst_in, buf1, NODES_PER_G, M1);
  conv_gemm_k<<<dim3(M1 / 128), b256, 0, stream>>>(buf0, W1r, buf1, W1n, b1, buf0, M1);
  pnorm_k<<<dim3(1), dim3(128), 0, stream>>>(p1, nrm);
  score_k<<<blocks(M1, 256), b256, 0, stream>>>(buf0, p1, nrm, score, M1);
  topk_sort_k<<<dim3(NUM_GRAPHS), dim3(512), 0, stream>>>(score, NODES_PER_G, k1, sel, mapping);
  pool_gather_k<<<blocks((long long)M2 * 32, 256), b256, 0, stream>>>(buf0, score, sel, buf1, M2);
  edge_remap_k<<<blocks(E, 256), b256, 0, stream>>>(src_in, dst_in, mapping, srcw, dstw, E);
  readout_k<<<dim3(NUM_GRAPHS), dim3(128), 0, stream>>>(buf1, k1, g);

  // ================= stage 2 (x = buf1) =================
  aggregate(buf1, srcw, dstw, buf0, k1, M2);
  conv_gemm_k<<<dim3(M2 / 128), b256, 0, stream>>>(buf1, W2r, buf0, W2n, b2, buf1, M2);
  pnorm_k<<<dim3(1), dim3(128), 0, stream>>>(p2, nrm);
  score_k<<<blocks(M2, 256), b256, 0, stream>>>(buf1, p2, nrm, score, M2);
  topk_sort_k<<<dim3(NUM_GRAPHS), dim3(512), 0, stream>>>(score, k1, k2, sel, mapping);
  pool_gather_k<<<blocks((long long)M3 * 32, 256), b256, 0, stream>>>(buf1, score, sel, buf0, M3);
  edge_remap_k<<<blocks(E, 256), b256, 0, stream>>>(srcw, dstw, mapping, srcw, dstw, E);
  readout_k<<<dim3(NUM_GRAPHS), dim3(128), 0, stream>>>(buf0, k2, g);

  // ================= stage 3 (x = buf0) =================
  aggregate(buf0, srcw, dstw, buf1, k2, M3);
  conv_gemm_k<<<dim3(M3 / 128), b256, 0, stream>>>(buf0, W3r, buf1, W3n, b3, buf0, M3);
  pnorm_k<<<dim3(1), dim3(128), 0, stream>>>(p3, nrm);
  score_k<<<blocks(M3, 256), b256, 0, stream>>>(buf0, p3, nrm, score, M3);
  topk_sort_k<<<dim3(NUM_GRAPHS), dim3(512), 0, stream>>>(score, k2, k3, sel, mapping);
  pool_gather_k<<<blocks((long long)M4 * 32, 256), b256, 0, stream>>>(buf0, score, sel, buf1, M4);
  readout_k<<<dim3(NUM_GRAPHS), dim3(128), 0, stream>>>(buf1, k3, g);

  // ================= head =================
  fc_k<<<blocks(256 * 128, 256), b256, 0, stream>>>(g, fc1_W, fc1_b, h1, 256, 256, 128);
  bn_relu_k<<<dim3(128), b256, 0, stream>>>(h1, bn1_g, bn1_b, 128);
  fc_k<<<blocks(256 * 64, 256), b256, 0, stream>>>(h1, fc2_W, fc2_b, h2, 256, 128, 64);
  bn_relu_k<<<dim3(64), b256, 0, stream>>>(h2, bn2_g, bn2_b, 64);

  // ================= final per-node sigmoid dot =================
  final_k<<<blocks(TN, 256), b256, 0, stream>>>(item_id, emb_item, h2, out, TN);
}

// Round 3
// 1090.869 us; speedup vs baseline: 2.8481x; 1.0277x over previous
//
#include <hip/hip_runtime.h>
#include <hip/hip_bf16.h>
#include <math.h>

// ---------------------------------------------------------------------------
// NetNode: 3x (GraphConv -> TopKPooling -> readout) + FC/BN head + per-node dot
// B=256, N=512, E=2048/graph, F=128, EMB=64. k1=461, k2=415, k3=374.
// R3: conv GEMM -> MFMA bf16x3 (split-precision, ~fp32 accuracy) with fused
//     score epilogue; aggregation -> per-graph LDS-staged CSR gather.
// ---------------------------------------------------------------------------

#define TOTAL_NODES 131072   // B*N
#define NUM_GRAPHS  256
#define NODES_PER_G 512
#define E_TOTAL     524288   // B*E
#define EPG         2048     // edges per graph (slot capacity)
#define FDIM        128
#define EMBD        64

typedef __bf16 bf16x8 __attribute__((ext_vector_type(8)));
typedef float  f32x4  __attribute__((ext_vector_type(4)));

static __device__ __forceinline__ f32x4 mfma16(bf16x8 a, bf16x8 b, f32x4 c) {
  return __builtin_amdgcn_mfma_f32_16x16x32_bf16(a, b, c, 0, 0, 0);
}

static inline size_t align256(size_t x) { return (x + 255) & ~size_t(255); }

// ---------------- gather embeddings: x[:,0:64]=emb_item[item], x[:,64:128]=emb_cat[cat]
__global__ __launch_bounds__(256) void gather_embed_k(
    const int* __restrict__ item_id, const int* __restrict__ cat_id,
    const float* __restrict__ emb_item, const float* __restrict__ emb_cat,
    float* __restrict__ x, int total)
{
  int i = blockIdx.x * 256 + threadIdx.x;
  int node = i >> 5, part = i & 31;
  if (node >= total) return;
  float4 v;
  if (part < 16) {
    v = *(const float4*)&emb_item[(size_t)item_id[node] * EMBD + part * 4];
  } else {
    v = *(const float4*)&emb_cat[(size_t)cat_id[node] * EMBD + (part - 16) * 4];
  }
  *(float4*)&x[(size_t)node * FDIM + part * 4] = v;
}

// ================= CSR build =================
__global__ __launch_bounds__(256) void csr_count_k(
    const int* __restrict__ dst, int* __restrict__ counts, int E)
{
  int e = blockIdx.x * 256 + threadIdx.x;
  if (e >= E) return;
  int d = dst[e];
  if (d < 0) return;
  atomicAdd(&counts[d], 1);
}

__global__ __launch_bounds__(512) void csr_scan_k(
    const int* __restrict__ counts, int n, int* __restrict__ off,
    int* __restrict__ cursor)
{
  __shared__ int s[512];
  int g = blockIdx.x, t = threadIdx.x;
  int v = (t < n) ? counts[g * n + t] : 0;
  s[t] = v;
  __syncthreads();
  for (int d = 1; d < 512; d <<= 1) {
    int add = (t >= d) ? s[t - d] : 0;
    __syncthreads();
    s[t] += add;
    __syncthreads();
  }
  if (t < n) {
    int abs_off = g * EPG + (s[t] - v);
    off[g * n + t] = abs_off;
    cursor[g * n + t] = abs_off;
  }
}

__global__ __launch_bounds__(256) void csr_scatter_k(
    const int* __restrict__ src, const int* __restrict__ dst,
    int* __restrict__ cursor, int* __restrict__ slots, int E)
{
  int e = blockIdx.x * 256 + threadIdx.x;
  if (e >= E) return;
  int d = dst[e];
  if (d < 0) return;
  int pos = atomicAdd(&cursor[d], 1);
  slots[pos] = src[e];
}

// ---------------- LDS-staged aggregation: agg[i] = sum_{e: dst=i} x[src_e]
// grid (NUM_GRAPHS, 4): block stages graph g's x[:, ch*32 .. +31] in LDS.
#define GCH  32
#define GPAD 36  // 144 B row stride (16B aligned, odd bank phase)
__global__ __launch_bounds__(256) void gather_lds_k(
    const float* __restrict__ x, const int* __restrict__ slots,
    const int* __restrict__ off, const int* __restrict__ counts,
    float* __restrict__ agg, int n_per_g)
{
  __shared__ float xs[NODES_PER_G * GPAD];   // 72 KB
  const int g = blockIdx.x, ch = blockIdx.y;
  const int tid = threadIdx.x;
  const int c0 = ch * GCH;
  const int rowbase = g * n_per_g;
  const int nv4 = n_per_g * 8;               // float4 count in tile
  for (int v = tid; v < nv4; v += 256) {
    int r = v >> 3, c4 = (v & 7) * 4;
    float4 t = *(const float4*)&x[(size_t)(rowbase + r) * FDIM + c0 + c4];
    *(float4*)&xs[r * GPAD + c4] = t;
  }
  __syncthreads();
  const int nlane = tid & 7;                 // 8 lanes x float4 = 32 feats
  const int nslot = tid >> 3;                // 32 nodes per iteration
  for (int n = nslot; n < n_per_g; n += 32) {
    int gn = rowbase + n;
    int deg = counts[gn];
    int base = off[gn];
    float4 a = make_float4(0.f, 0.f, 0.f, 0.f);
    for (int d = 0; d < deg; ++d) {
      int s = slots[base + d] - rowbase;     // local row
      float4 v = *(const float4*)&xs[s * GPAD + nlane * 4];
      a.x += v.x; a.y += v.y; a.z += v.z; a.w += v.w;
    }
    *(float4*)&agg[(size_t)gn * FDIM + c0 + nlane * 4] = a;
  }
}

// ---------------- C[M,128] = relu(A1@W1 + A2@W2 + b) via bf16x3 MFMA.
// Also fused: score[row] = (C[row,:] . p) / ||p||.
// Block 256 thr = 4 waves; 128x128 tile; wave w owns rows w*32..+32.
// In-place safe (C may == A1: all A1 reads precede C writes within the block,
// and blocks only touch their own 128-row range).
__global__ __launch_bounds__(256) void conv_mfma_k(
    const float* __restrict__ A1, const float* __restrict__ W1,
    const float* __restrict__ A2, const float* __restrict__ W2,
    const float* __restrict__ bias, const float* __restrict__ p,
    const float* __restrict__ nrm, float* __restrict__ C,
    float* __restrict__ score, int M)
{
  __shared__ __bf16 Ah[128 * 72];   // 128 rows x 64 K (+8 pad), 18 KB each
  __shared__ __bf16 Al[128 * 72];
  __shared__ __bf16 Bh[128 * 72];   // W transposed: [col][k]
  __shared__ __bf16 Bl[128 * 72];

  const int tid  = threadIdx.x;
  const int lane = tid & 63;
  const int w    = tid >> 6;
  const int row0 = blockIdx.x * 128;
  const int l15  = lane & 15;
  const int lg   = lane >> 4;

  f32x4 acc[2][8];
#pragma unroll
  for (int rf = 0; rf < 2; ++rf)
#pragma unroll
    for (int cf = 0; cf < 8; ++cf) acc[rf][cf] = (f32x4){0.f, 0.f, 0.f, 0.f};

  for (int pass = 0; pass < 2; ++pass) {
    const float* __restrict__ A = pass ? A2 : A1;
    const float* __restrict__ W = pass ? W2 : W1;
    for (int half = 0; half < 2; ++half) {
      const int k0 = half * 64;
      __syncthreads();  // prior-phase LDS reads complete before overwrite
      // A tile 128x64 -> hi/lo bf16
#pragma unroll
      for (int q = 0; q < 8; ++q) {
        int v = q * 256 + tid;
        int r = v >> 4, c4 = (v & 15) * 4;
        float4 t = *(const float4*)&A[(size_t)(row0 + r) * FDIM + k0 + c4];
        float f[4] = {t.x, t.y, t.z, t.w};
#pragma unroll
        for (int j = 0; j < 4; ++j) {
          __bf16 h = (__bf16)f[j];
          Ah[r * 72 + c4 + j] = h;
          Al[r * 72 + c4 + j] = (__bf16)(f[j] - (float)h);
        }
      }
      // W tile 64x128 -> transposed hi/lo bf16
#pragma unroll
      for (int q = 0; q < 8; ++q) {
        int v = q * 256 + tid;
        int kk = v >> 5, n4 = (v & 31) * 4;
        float4 t = *(const float4*)&W[(size_t)(k0 + kk) * FDIM + n4];
        float f[4] = {t.x, t.y, t.z, t.w};
#pragma unroll
        for (int j = 0; j < 4; ++j) {
          __bf16 h = (__bf16)f[j];
          Bh[(n4 + j) * 72 + kk] = h;
          Bl[(n4 + j) * 72 + kk] = (__bf16)(f[j] - (float)h);
        }
      }
      __syncthreads();
#pragma unroll
      for (int kc = 0; kc < 2; ++kc) {
        const int koff = kc * 32 + lg * 8;
        const int ar = (w * 32 + l15) * 72 + koff;
        bf16x8 ah0 = *(const bf16x8*)&Ah[ar];
        bf16x8 al0 = *(const bf16x8*)&Al[ar];
        bf16x8 ah1 = *(const bf16x8*)&Ah[ar + 16 * 72];
        bf16x8 al1 = *(const bf16x8*)&Al[ar + 16 * 72];
#pragma unroll
        for (int cf = 0; cf < 8; ++cf) {
          const int bo = (cf * 16 + l15) * 72 + koff;
          bf16x8 bh = *(const bf16x8*)&Bh[bo];
          bf16x8 bl = *(const bf16x8*)&Bl[bo];
          acc[0][cf] = mfma16(ah0, bh, acc[0][cf]);
          acc[0][cf] = mfma16(ah0, bl, acc[0][cf]);
          acc[0][cf] = mfma16(al0, bh, acc[0][cf]);
          acc[1][cf] = mfma16(ah1, bh, acc[1][cf]);
          acc[1][cf] = mfma16(ah1, bl, acc[1][cf]);
          acc[1][cf] = mfma16(al1, bh, acc[1][cf]);
        }
      }
    }
  }

  // epilogue: bias+relu, store, fused score (row . p / ||p||)
  const float nv = nrm[0];
  float bv[8], pv[8];
#pragma unroll
  for (int cf = 0; cf < 8; ++cf) {
    int col = cf * 16 + l15;
    bv[cf] = bias[col];
    pv[cf] = p[col];
  }
#pragma unroll
  for (int rf = 0; rf < 2; ++rf) {
#pragma unroll
    for (int j = 0; j < 4; ++j) {
      int row = row0 + w * 32 + rf * 16 + lg * 4 + j;
      float* crow = &C[(size_t)row * FDIM];
      float rsv = 0.f;
#pragma unroll
      for (int cf = 0; cf < 8; ++cf) {
        float val = acc[rf][cf][j] + bv[cf];
        val = fmaxf(val, 0.f);
        crow[cf * 16 + l15] = val;
        rsv += val * pv[cf];
      }
      rsv += __shfl_xor(rsv, 1, 16);
      rsv += __shfl_xor(rsv, 2, 16);
      rsv += __shfl_xor(rsv, 4, 16);
      rsv += __shfl_xor(rsv, 8, 16);
      if (l15 == 0) score[row] = rsv / nv;
    }
  }
}

// ---------------- ||p|| (128 elems)
__global__ __launch_bounds__(128) void pnorm_k(const float* __restrict__ p,
                                               float* __restrict__ nrm)
{
  __shared__ float ss[128];
  int t = threadIdx.x;
  float v = p[t];
  ss[t] = v * v;
  __syncthreads();
  for (int s = 64; s > 0; s >>= 1) {
    if (t < s) ss[t] += ss[t + s];
    __syncthreads();
  }
  if (t == 0) nrm[0] = sqrtf(ss[0]);
}

// ---------------- per-graph top-k via bitonic sort
__global__ __launch_bounds__(512) void topk_sort_k(
    const float* __restrict__ score, int n_old, int k_new,
    int* __restrict__ sel, int* __restrict__ mapping)
{
  __shared__ float sv[512];
  __shared__ int   si[512];
  int b = blockIdx.x, t = threadIdx.x;
  sv[t] = (t < n_old) ? -score[(size_t)b * n_old + t] : 3.0e38f;
  si[t] = t;
  __syncthreads();
  for (int k = 2; k <= 512; k <<= 1) {
    for (int j = k >> 1; j > 0; j >>= 1) {
      int ixj = t ^ j;
      if (ixj > t) {
        bool up = ((t & k) == 0);
        float a = sv[t], c = sv[ixj];
        if ((a > c) == up) {
          sv[t] = c; sv[ixj] = a;
          int tmp = si[t]; si[t] = si[ixj]; si[ixj] = tmp;
        }
      }
      __syncthreads();
    }
  }
  if (t < n_old) {
    int old_g = b * n_old + si[t];
    if (t < k_new) {
      sel[b * k_new + t] = old_g;
      mapping[old_g] = b * k_new + t;
    } else {
      mapping[old_g] = -1;
    }
  }
}

// ---------------- pooled gather with tanh(score) gate
__global__ __launch_bounds__(256) void pool_gather_k(
    const float* __restrict__ x, const float* __restrict__ score,
    const int* __restrict__ sel, float* __restrict__ xout, int Mnew)
{
  int i = blockIdx.x * 256 + threadIdx.x;
  int node = i >> 5, part = i & 31;
  if (node >= Mnew) return;
  int old = sel[node];
  float g = tanhf(score[old]);
  float4 v = *(const float4*)&x[(size_t)old * FDIM + part * 4];
  v.x *= g; v.y *= g; v.z *= g; v.w *= g;
  *(float4*)&xout[(size_t)node * FDIM + part * 4] = v;
}

// ---------------- edge remap (in-place safe)
__global__ __launch_bounds__(256) void edge_remap_k(
    const int* __restrict__ src_in, const int* __restrict__ dst_in,
    const int* __restrict__ mapping, int* __restrict__ src_out,
    int* __restrict__ dst_out, int E)
{
  int e = blockIdx.x * 256 + threadIdx.x;
  if (e >= E) return;
  int s = src_in[e], d = dst_in[e];
  int ns = (s >= 0) ? mapping[s] : -1;
  int nd = (d >= 0) ? mapping[d] : -1;
  if (ns < 0 || nd < 0) { ns = -1; nd = -1; }
  src_out[e] = ns;
  dst_out[e] = nd;
}

// ---------------- readout: g[b,0:128] += max, g[b,128:256] += mean
__global__ __launch_bounds__(128) void readout_k(
    const float* __restrict__ x, int k, float* __restrict__ g)
{
  int b = blockIdx.x, c = threadIdx.x;
  const float* base = x + (size_t)b * k * FDIM + c;
  float mx = -3.0e38f, sm = 0.f;
  for (int r = 0; r < k; ++r) {
    float v = base[(size_t)r * FDIM];
    mx = fmaxf(mx, v);
    sm += v;
  }
  g[b * 256 + c]       += mx;
  g[b * 256 + 128 + c] += sm / (float)k;
}

// ---------------- fc
__global__ __launch_bounds__(256) void fc_k(
    const float* __restrict__ in, const float* __restrict__ W,
    const float* __restrict__ bias, float* __restrict__ out,
    int rows, int K, int C)
{
  int idx = blockIdx.x * 256 + threadIdx.x;
  if (idx >= rows * C) return;
  int row = idx / C, c = idx % C;
  float s = bias[c];
  const float* grow = &in[(size_t)row * K];
  for (int t = 0; t < K; ++t) s += grow[t] * W[(size_t)t * C + c];
  out[idx] = s;
}

// ---------------- BatchNorm (training stats over 256 rows) + relu
__global__ __launch_bounds__(256) void bn_relu_k(
    float* __restrict__ h, const float* __restrict__ gamma,
    const float* __restrict__ beta, int C)
{
  __shared__ float ssum[256], ssq[256];
  int c = blockIdx.x, r = threadIdx.x;
  float v = h[(size_t)r * C + c];
  ssum[r] = v; ssq[r] = v * v;
  __syncthreads();
  for (int s = 128; s > 0; s >>= 1) {
    if (r < s) { ssum[r] += ssum[r + s]; ssq[r] += ssq[r + s]; }
    __syncthreads();
  }
  float m = ssum[0] * (1.f / 256.f);
  float var = ssq[0] * (1.f / 256.f) - m * m;
  float o = gamma[c] * (v - m) * rsqrtf(var + 1e-5f) + beta[c];
  h[(size_t)r * C + c] = fmaxf(o, 0.f);
}

// ---------------- out[nid] = sigmoid(dot(emb_item[item_id[nid]], g2[graph]))
__global__ __launch_bounds__(256) void final_k(
    const int* __restrict__ item_id, const float* __restrict__ emb_item,
    const float* __restrict__ g2, float* __restrict__ out, int total)
{
  int nid = blockIdx.x * 256 + threadIdx.x;
  if (nid >= total) return;
  int b = nid >> 9;
  const float* e = &emb_item[(size_t)item_id[nid] * EMBD];
  const float* gg = &g2[(size_t)b * 64];
  float s = 0.f;
#pragma unroll
  for (int j = 0; j < 64; j += 4) {
    float4 a = *(const float4*)&e[j];
    float4 c = *(const float4*)&gg[j];
    s += a.x * c.x + a.y * c.y + a.z * c.z + a.w * c.w;
  }
  out[nid] = 1.f / (1.f + expf(-s));
}

// ---------------------------------------------------------------------------
extern "C" void kernel_launch(void* const* d_in, const int* in_sizes, int n_in,
                              void* d_out, int out_size, void* d_ws, size_t ws_size,
                              hipStream_t stream)
{
  const int*   item_id  = (const int*)  d_in[0];
  const int*   cat_id   = (const int*)  d_in[1];
  const int*   src_in   = (const int*)  d_in[2];
  const int*   dst_in   = (const int*)  d_in[3];
  const float* emb_item = (const float*)d_in[4];
  const float* emb_cat  = (const float*)d_in[5];
  const float* W1r = (const float*)d_in[6];
  const float* W1n = (const float*)d_in[7];
  const float* b1  = (const float*)d_in[8];
  const float* p1  = (const float*)d_in[9];
  const float* W2r = (const float*)d_in[10];
  const float* W2n = (const float*)d_in[11];
  const float* b2  = (const float*)d_in[12];
  const float* p2  = (const float*)d_in[13];
  const float* W3r = (const float*)d_in[14];
  const float* W3n = (const float*)d_in[15];
  const float* b3  = (const float*)d_in[16];
  const float* p3  = (const float*)d_in[17];
  const float* fc1_W = (const float*)d_in[18];
  const float* fc1_b = (const float*)d_in[19];
  const float* bn1_g = (const float*)d_in[20];
  const float* bn1_b = (const float*)d_in[21];
  const float* fc2_W = (const float*)d_in[22];
  const float* fc2_b = (const float*)d_in[23];
  const float* bn2_g = (const float*)d_in[24];
  const float* bn2_b = (const float*)d_in[25];
  float* out = (float*)d_out;

  const int TN = TOTAL_NODES;
  const int E  = E_TOTAL;
  const int k1 = 461, k2 = 415, k3 = 374;
  const int M1 = TN;              // 131072
  const int M2 = NUM_GRAPHS * k1; // 118016
  const int M3 = NUM_GRAPHS * k2; // 106240
  const int M4 = NUM_GRAPHS * k3; // 95744

  char* ws = (char*)d_ws;
  size_t off = 0;
  auto carve = [&](size_t bytes) { char* p = ws + off; off += align256(bytes); return p; };
  float* buf0   = (float*)carve((size_t)TN * FDIM * 4);
  float* buf1   = (float*)carve((size_t)TN * FDIM * 4);
  float* score  = (float*)carve((size_t)TN * 4);
  int*   sel    = (int*)  carve((size_t)TN * 4);
  int*   mapping= (int*)  carve((size_t)TN * 4);
  int*   srcw   = (int*)  carve((size_t)E * 4);
  int*   dstw   = (int*)  carve((size_t)E * 4);
  int*   counts = (int*)  carve((size_t)TN * 4);
  int*   offs   = (int*)  carve((size_t)TN * 4);
  int*   cursor = (int*)  carve((size_t)TN * 4);
  int*   slots  = (int*)  carve((size_t)E * 4);
  float* g      = (float*)carve(256 * 256 * 4);
  float* h1     = (float*)carve(256 * 128 * 4);
  float* h2     = (float*)carve(256 * 64 * 4);
  float* nrm    = (float*)carve(256);
  if (off > ws_size) return;

  dim3 b256(256);
  auto blocks = [](long long work, int bs) { return dim3((unsigned)((work + bs - 1) / bs)); };

  // aggregation: CSR build + LDS-staged gather
  auto aggregate = [&](const float* x, const int* s, const int* d, float* agg,
                       int n_per_g, int M) {
    hipMemsetAsync(counts, 0, (size_t)M * 4, stream);
    csr_count_k<<<blocks(E, 256), b256, 0, stream>>>(d, counts, E);
    csr_scan_k<<<dim3(NUM_GRAPHS), dim3(512), 0, stream>>>(counts, n_per_g, offs, cursor);
    csr_scatter_k<<<blocks(E, 256), b256, 0, stream>>>(s, d, cursor, slots, E);
    gather_lds_k<<<dim3(NUM_GRAPHS, 4), b256, 0, stream>>>(x, slots, offs, counts, agg, n_per_g);
  };

  hipMemsetAsync(g, 0, 256 * 256 * 4, stream);

  gather_embed_k<<<blocks((long long)TN * 32, 256), b256, 0, stream>>>(
      item_id, cat_id, emb_item, emb_cat, buf0, TN);

  // ================= stage 1 (x = buf0) =================
  pnorm_k<<<dim3(1), dim3(128), 0, stream>>>(p1, nrm);
  aggregate(buf0, src_in, dst_in, buf1, NODES_PER_G, M1);
  conv_mfma_k<<<dim3(M1 / 128), b256, 0, stream>>>(
      buf0, W1r, buf1, W1n, b1, p1, nrm, buf0, score, M1);
  topk_sort_k<<<dim3(NUM_GRAPHS), dim3(512), 0, stream>>>(score, NODES_PER_G, k1, sel, mapping);
  pool_gather_k<<<blocks((long long)M2 * 32, 256), b256, 0, stream>>>(buf0, score, sel, buf1, M2);
  edge_remap_k<<<blocks(E, 256), b256, 0, stream>>>(src_in, dst_in, mapping, srcw, dstw, E);
  readout_k<<<dim3(NUM_GRAPHS), dim3(128), 0, stream>>>(buf1, k1, g);

  // ================= stage 2 (x = buf1) =================
  pnorm_k<<<dim3(1), dim3(128), 0, stream>>>(p2, nrm);
  aggregate(buf1, srcw, dstw, buf0, k1, M2);
  conv_mfma_k<<<dim3(M2 / 128), b256, 0, stream>>>(
      buf1, W2r, buf0, W2n, b2, p2, nrm, buf1, score, M2);
  topk_sort_k<<<dim3(NUM_GRAPHS), dim3(512), 0, stream>>>(score, k1, k2, sel, mapping);
  pool_gather_k<<<blocks((long long)M3 * 32, 256), b256, 0, stream>>>(buf1, score, sel, buf0, M3);
  edge_remap_k<<<blocks(E, 256), b256, 0, stream>>>(srcw, dstw, mapping, srcw, dstw, E);
  readout_k<<<dim3(NUM_GRAPHS), dim3(128), 0, stream>>>(buf0, k2, g);

  // ================= stage 3 (x = buf0) =================
  pnorm_k<<<dim3(1), dim3(128), 0, stream>>>(p3, nrm);
  aggregate(buf0, srcw, dstw, buf1, k2, M3);
  conv_mfma_k<<<dim3(M3 / 128), b256, 0, stream>>>(
      buf0, W3r, buf1, W3n, b3, p3, nrm, buf0, score, M3);
  topk_sort_k<<<dim3(NUM_GRAPHS), dim3(512), 0, stream>>>(score, k2, k3, sel, mapping);
  pool_gather_k<<<blocks((long long)M4 * 32, 256), b256, 0, stream>>>(buf0, score, sel, buf1, M4);
  readout_k<<<dim3(NUM_GRAPHS), dim3(128), 0, stream>>>(buf1, k3, g);

  // ================= head =================
  fc_k<<<blocks(256 * 128, 256), b256, 0, stream>>>(g, fc1_W, fc1_b, h1, 256, 256, 128);
  bn_relu_k<<<dim3(128), b256, 0, stream>>>(h1, bn1_g, bn1_b, 128);
  fc_k<<<blocks(256 * 64, 256), b256, 0, stream>>>(h1, fc2_W, fc2_b, h2, 256, 128, 64);
  bn_relu_k<<<dim3(64), b256, 0, stream>>>(h2, bn2_g, bn2_b, 64);

  final_k<<<blocks(TN, 256), b256, 0, stream>>>(item_id, emb_item, h2, out, TN);
}

// Round 4
// 775.938 us; speedup vs baseline: 4.0041x; 1.4059x over previous
//
#include <hip/hip_runtime.h>
#include <hip/hip_bf16.h>
#include <math.h>

// ---------------------------------------------------------------------------
// NetNode: 3x (GraphConv -> TopKPooling -> readout) + FC/BN head + per-node dot
// B=256, N=512, E=2048/graph, F=128, EMB=64. k1=461, k2=415, k3=374.
// R4: readout fused into pool_gather (readout_k was 363us latency-bound).
// ---------------------------------------------------------------------------

#define TOTAL_NODES 131072   // B*N
#define NUM_GRAPHS  256
#define NODES_PER_G 512
#define E_TOTAL     524288   // B*E
#define EPG         2048     // edges per graph (slot capacity)
#define FDIM        128
#define EMBD        64

typedef __bf16 bf16x8 __attribute__((ext_vector_type(8)));
typedef float  f32x4  __attribute__((ext_vector_type(4)));

static __device__ __forceinline__ f32x4 mfma16(bf16x8 a, bf16x8 b, f32x4 c) {
  return __builtin_amdgcn_mfma_f32_16x16x32_bf16(a, b, c, 0, 0, 0);
}

static inline size_t align256(size_t x) { return (x + 255) & ~size_t(255); }

// ---------------- gather embeddings
__global__ __launch_bounds__(256) void gather_embed_k(
    const int* __restrict__ item_id, const int* __restrict__ cat_id,
    const float* __restrict__ emb_item, const float* __restrict__ emb_cat,
    float* __restrict__ x, int total)
{
  int i = blockIdx.x * 256 + threadIdx.x;
  int node = i >> 5, part = i & 31;
  if (node >= total) return;
  float4 v;
  if (part < 16) {
    v = *(const float4*)&emb_item[(size_t)item_id[node] * EMBD + part * 4];
  } else {
    v = *(const float4*)&emb_cat[(size_t)cat_id[node] * EMBD + (part - 16) * 4];
  }
  *(float4*)&x[(size_t)node * FDIM + part * 4] = v;
}

// ================= CSR build =================
__global__ __launch_bounds__(256) void csr_count_k(
    const int* __restrict__ dst, int* __restrict__ counts, int E)
{
  int e = blockIdx.x * 256 + threadIdx.x;
  if (e >= E) return;
  int d = dst[e];
  if (d < 0) return;
  atomicAdd(&counts[d], 1);
}

__global__ __launch_bounds__(512) void csr_scan_k(
    const int* __restrict__ counts, int n, int* __restrict__ off,
    int* __restrict__ cursor)
{
  __shared__ int s[512];
  int g = blockIdx.x, t = threadIdx.x;
  int v = (t < n) ? counts[g * n + t] : 0;
  s[t] = v;
  __syncthreads();
  for (int d = 1; d < 512; d <<= 1) {
    int add = (t >= d) ? s[t - d] : 0;
    __syncthreads();
    s[t] += add;
    __syncthreads();
  }
  if (t < n) {
    int abs_off = g * EPG + (s[t] - v);
    off[g * n + t] = abs_off;
    cursor[g * n + t] = abs_off;
  }
}

__global__ __launch_bounds__(256) void csr_scatter_k(
    const int* __restrict__ src, const int* __restrict__ dst,
    int* __restrict__ cursor, int* __restrict__ slots, int E)
{
  int e = blockIdx.x * 256 + threadIdx.x;
  if (e >= E) return;
  int d = dst[e];
  if (d < 0) return;
  int pos = atomicAdd(&cursor[d], 1);
  slots[pos] = src[e];
}

// ---------------- LDS-staged aggregation
#define GCH  32
#define GPAD 36
__global__ __launch_bounds__(256) void gather_lds_k(
    const float* __restrict__ x, const int* __restrict__ slots,
    const int* __restrict__ off, const int* __restrict__ counts,
    float* __restrict__ agg, int n_per_g)
{
  __shared__ float xs[NODES_PER_G * GPAD];
  const int g = blockIdx.x, ch = blockIdx.y;
  const int tid = threadIdx.x;
  const int c0 = ch * GCH;
  const int rowbase = g * n_per_g;
  const int nv4 = n_per_g * 8;
  for (int v = tid; v < nv4; v += 256) {
    int r = v >> 3, c4 = (v & 7) * 4;
    float4 t = *(const float4*)&x[(size_t)(rowbase + r) * FDIM + c0 + c4];
    *(float4*)&xs[r * GPAD + c4] = t;
  }
  __syncthreads();
  const int nlane = tid & 7;
  const int nslot = tid >> 3;
  for (int n = nslot; n < n_per_g; n += 32) {
    int gn = rowbase + n;
    int deg = counts[gn];
    int base = off[gn];
    float4 a = make_float4(0.f, 0.f, 0.f, 0.f);
    for (int d = 0; d < deg; ++d) {
      int s = slots[base + d] - rowbase;
      float4 v = *(const float4*)&xs[s * GPAD + nlane * 4];
      a.x += v.x; a.y += v.y; a.z += v.z; a.w += v.w;
    }
    *(float4*)&agg[(size_t)gn * FDIM + c0 + nlane * 4] = a;
  }
}

// ---------------- C[M,128] = relu(A1@W1 + A2@W2 + b) via bf16x3 MFMA + fused score
__global__ __launch_bounds__(256) void conv_mfma_k(
    const float* __restrict__ A1, const float* __restrict__ W1,
    const float* __restrict__ A2, const float* __restrict__ W2,
    const float* __restrict__ bias, const float* __restrict__ p,
    const float* __restrict__ nrm, float* __restrict__ C,
    float* __restrict__ score, int M)
{
  __shared__ __bf16 Ah[128 * 72];
  __shared__ __bf16 Al[128 * 72];
  __shared__ __bf16 Bh[128 * 72];
  __shared__ __bf16 Bl[128 * 72];

  const int tid  = threadIdx.x;
  const int lane = tid & 63;
  const int w    = tid >> 6;
  const int row0 = blockIdx.x * 128;
  const int l15  = lane & 15;
  const int lg   = lane >> 4;

  f32x4 acc[2][8];
#pragma unroll
  for (int rf = 0; rf < 2; ++rf)
#pragma unroll
    for (int cf = 0; cf < 8; ++cf) acc[rf][cf] = (f32x4){0.f, 0.f, 0.f, 0.f};

  for (int pass = 0; pass < 2; ++pass) {
    const float* __restrict__ A = pass ? A2 : A1;
    const float* __restrict__ W = pass ? W2 : W1;
    for (int half = 0; half < 2; ++half) {
      const int k0 = half * 64;
      __syncthreads();
#pragma unroll
      for (int q = 0; q < 8; ++q) {
        int v = q * 256 + tid;
        int r = v >> 4, c4 = (v & 15) * 4;
        float4 t = *(const float4*)&A[(size_t)(row0 + r) * FDIM + k0 + c4];
        float f[4] = {t.x, t.y, t.z, t.w};
#pragma unroll
        for (int j = 0; j < 4; ++j) {
          __bf16 h = (__bf16)f[j];
          Ah[r * 72 + c4 + j] = h;
          Al[r * 72 + c4 + j] = (__bf16)(f[j] - (float)h);
        }
      }
#pragma unroll
      for (int q = 0; q < 8; ++q) {
        int v = q * 256 + tid;
        int kk = v >> 5, n4 = (v & 31) * 4;
        float4 t = *(const float4*)&W[(size_t)(k0 + kk) * FDIM + n4];
        float f[4] = {t.x, t.y, t.z, t.w};
#pragma unroll
        for (int j = 0; j < 4; ++j) {
          __bf16 h = (__bf16)f[j];
          Bh[(n4 + j) * 72 + kk] = h;
          Bl[(n4 + j) * 72 + kk] = (__bf16)(f[j] - (float)h);
        }
      }
      __syncthreads();
#pragma unroll
      for (int kc = 0; kc < 2; ++kc) {
        const int koff = kc * 32 + lg * 8;
        const int ar = (w * 32 + l15) * 72 + koff;
        bf16x8 ah0 = *(const bf16x8*)&Ah[ar];
        bf16x8 al0 = *(const bf16x8*)&Al[ar];
        bf16x8 ah1 = *(const bf16x8*)&Ah[ar + 16 * 72];
        bf16x8 al1 = *(const bf16x8*)&Al[ar + 16 * 72];
#pragma unroll
        for (int cf = 0; cf < 8; ++cf) {
          const int bo = (cf * 16 + l15) * 72 + koff;
          bf16x8 bh = *(const bf16x8*)&Bh[bo];
          bf16x8 bl = *(const bf16x8*)&Bl[bo];
          acc[0][cf] = mfma16(ah0, bh, acc[0][cf]);
          acc[0][cf] = mfma16(ah0, bl, acc[0][cf]);
          acc[0][cf] = mfma16(al0, bh, acc[0][cf]);
          acc[1][cf] = mfma16(ah1, bh, acc[1][cf]);
          acc[1][cf] = mfma16(ah1, bl, acc[1][cf]);
          acc[1][cf] = mfma16(al1, bh, acc[1][cf]);
        }
      }
    }
  }

  const float nv = nrm[0];
  float bv[8], pv[8];
#pragma unroll
  for (int cf = 0; cf < 8; ++cf) {
    int col = cf * 16 + l15;
    bv[cf] = bias[col];
    pv[cf] = p[col];
  }
#pragma unroll
  for (int rf = 0; rf < 2; ++rf) {
#pragma unroll
    for (int j = 0; j < 4; ++j) {
      int row = row0 + w * 32 + rf * 16 + lg * 4 + j;
      float* crow = &C[(size_t)row * FDIM];
      float rsv = 0.f;
#pragma unroll
      for (int cf = 0; cf < 8; ++cf) {
        float val = acc[rf][cf][j] + bv[cf];
        val = fmaxf(val, 0.f);
        crow[cf * 16 + l15] = val;
        rsv += val * pv[cf];
      }
      rsv += __shfl_xor(rsv, 1, 16);
      rsv += __shfl_xor(rsv, 2, 16);
      rsv += __shfl_xor(rsv, 4, 16);
      rsv += __shfl_xor(rsv, 8, 16);
      if (l15 == 0) score[row] = rsv / nv;
    }
  }
}

// ---------------- ||p||
__global__ __launch_bounds__(128) void pnorm_k(const float* __restrict__ p,
                                               float* __restrict__ nrm)
{
  __shared__ float ss[128];
  int t = threadIdx.x;
  float v = p[t];
  ss[t] = v * v;
  __syncthreads();
  for (int s = 64; s > 0; s >>= 1) {
    if (t < s) ss[t] += ss[t + s];
    __syncthreads();
  }
  if (t == 0) nrm[0] = sqrtf(ss[0]);
}

// ---------------- per-graph top-k via bitonic sort
__global__ __launch_bounds__(512) void topk_sort_k(
    const float* __restrict__ score, int n_old, int k_new,
    int* __restrict__ sel, int* __restrict__ mapping)
{
  __shared__ float sv[512];
  __shared__ int   si[512];
  int b = blockIdx.x, t = threadIdx.x;
  sv[t] = (t < n_old) ? -score[(size_t)b * n_old + t] : 3.0e38f;
  si[t] = t;
  __syncthreads();
  for (int k = 2; k <= 512; k <<= 1) {
    for (int j = k >> 1; j > 0; j >>= 1) {
      int ixj = t ^ j;
      if (ixj > t) {
        bool up = ((t & k) == 0);
        float a = sv[t], c = sv[ixj];
        if ((a > c) == up) {
          sv[t] = c; sv[ixj] = a;
          int tmp = si[t]; si[t] = si[ixj]; si[ixj] = tmp;
        }
      }
      __syncthreads();
    }
  }
  if (t < n_old) {
    int old_g = b * n_old + si[t];
    if (t < k_new) {
      sel[b * k_new + t] = old_g;
      mapping[old_g] = b * k_new + t;
    } else {
      mapping[old_g] = -1;
    }
  }
}

// ---------------- pooled gather + fused readout
// grid (NUM_GRAPHS, 4); block 256 = 32 node-slots x 8 float4-lanes.
// xout[new] = x[sel[new]] * tanh(score[sel[new]]) for feature chunk ch*32..+31,
// plus g[b, c] += max over rows, g[b, 128+c] += mean over rows.
__global__ __launch_bounds__(256) void pool_readout_k(
    const float* __restrict__ x, const float* __restrict__ score,
    const int* __restrict__ sel, float* __restrict__ xout,
    float* __restrict__ g, int k)
{
  __shared__ float lmx[32 * 36];
  __shared__ float lsm[32 * 36];
  const int b = blockIdx.x, ch = blockIdx.y;
  const int c0 = ch * 32;
  const int tid = threadIdx.x;
  const int lane = tid & 7;     // 8 lanes x float4 = 32 feats
  const int slot = tid >> 3;    // 32 node slots
  float4 mx = make_float4(-3.0e38f, -3.0e38f, -3.0e38f, -3.0e38f);
  float4 sm = make_float4(0.f, 0.f, 0.f, 0.f);
  for (int n = slot; n < k; n += 32) {
    int node = b * k + n;
    int old = sel[node];
    float gate = tanhf(score[old]);
    float4 v = *(const float4*)&x[(size_t)old * FDIM + c0 + lane * 4];
    v.x *= gate; v.y *= gate; v.z *= gate; v.w *= gate;
    *(float4*)&xout[(size_t)node * FDIM + c0 + lane * 4] = v;
    mx.x = fmaxf(mx.x, v.x); mx.y = fmaxf(mx.y, v.y);
    mx.z = fmaxf(mx.z, v.z); mx.w = fmaxf(mx.w, v.w);
    sm.x += v.x; sm.y += v.y; sm.z += v.z; sm.w += v.w;
  }
  float* pm = &lmx[slot * 36 + lane * 4];
  float* ps = &lsm[slot * 36 + lane * 4];
  pm[0] = mx.x; pm[1] = mx.y; pm[2] = mx.z; pm[3] = mx.w;
  ps[0] = sm.x; ps[1] = sm.y; ps[2] = sm.z; ps[3] = sm.w;
  __syncthreads();
  for (int s = 16; s > 0; s >>= 1) {
    if (slot < s) {
#pragma unroll
      for (int j = 0; j < 4; ++j) {
        int a = slot * 36 + lane * 4 + j;
        int bb = (slot + s) * 36 + lane * 4 + j;
        lmx[a] = fmaxf(lmx[a], lmx[bb]);
        lsm[a] += lsm[bb];
      }
    }
    __syncthreads();
  }
  if (slot == 0) {
    float inv_k = 1.f / (float)k;
#pragma unroll
    for (int j = 0; j < 4; ++j) {
      int c = c0 + lane * 4 + j;
      g[b * 256 + c]       += lmx[lane * 4 + j];
      g[b * 256 + 128 + c] += lsm[lane * 4 + j] * inv_k;
    }
  }
}

// ---------------- edge remap (in-place safe)
__global__ __launch_bounds__(256) void edge_remap_k(
    const int* __restrict__ src_in, const int* __restrict__ dst_in,
    const int* __restrict__ mapping, int* __restrict__ src_out,
    int* __restrict__ dst_out, int E)
{
  int e = blockIdx.x * 256 + threadIdx.x;
  if (e >= E) return;
  int s = src_in[e], d = dst_in[e];
  int ns = (s >= 0) ? mapping[s] : -1;
  int nd = (d >= 0) ? mapping[d] : -1;
  if (ns < 0 || nd < 0) { ns = -1; nd = -1; }
  src_out[e] = ns;
  dst_out[e] = nd;
}

// ---------------- fc
__global__ __launch_bounds__(256) void fc_k(
    const float* __restrict__ in, const float* __restrict__ W,
    const float* __restrict__ bias, float* __restrict__ out,
    int rows, int K, int C)
{
  int idx = blockIdx.x * 256 + threadIdx.x;
  if (idx >= rows * C) return;
  int row = idx / C, c = idx % C;
  float s = bias[c];
  const float* grow = &in[(size_t)row * K];
  for (int t = 0; t < K; ++t) s += grow[t] * W[(size_t)t * C + c];
  out[idx] = s;
}

// ---------------- BatchNorm (training stats over 256 rows) + relu
__global__ __launch_bounds__(256) void bn_relu_k(
    float* __restrict__ h, const float* __restrict__ gamma,
    const float* __restrict__ beta, int C)
{
  __shared__ float ssum[256], ssq[256];
  int c = blockIdx.x, r = threadIdx.x;
  float v = h[(size_t)r * C + c];
  ssum[r] = v; ssq[r] = v * v;
  __syncthreads();
  for (int s = 128; s > 0; s >>= 1) {
    if (r < s) { ssum[r] += ssum[r + s]; ssq[r] += ssq[r + s]; }
    __syncthreads();
  }
  float m = ssum[0] * (1.f / 256.f);
  float var = ssq[0] * (1.f / 256.f) - m * m;
  float o = gamma[c] * (v - m) * rsqrtf(var + 1e-5f) + beta[c];
  h[(size_t)r * C + c] = fmaxf(o, 0.f);
}

// ---------------- out[nid] = sigmoid(dot(emb_item[item_id[nid]], g2[graph]))
__global__ __launch_bounds__(256) void final_k(
    const int* __restrict__ item_id, const float* __restrict__ emb_item,
    const float* __restrict__ g2, float* __restrict__ out, int total)
{
  int nid = blockIdx.x * 256 + threadIdx.x;
  if (nid >= total) return;
  int b = nid >> 9;
  const float* e = &emb_item[(size_t)item_id[nid] * EMBD];
  const float* gg = &g2[(size_t)b * 64];
  float s = 0.f;
#pragma unroll
  for (int j = 0; j < 64; j += 4) {
    float4 a = *(const float4*)&e[j];
    float4 c = *(const float4*)&gg[j];
    s += a.x * c.x + a.y * c.y + a.z * c.z + a.w * c.w;
  }
  out[nid] = 1.f / (1.f + expf(-s));
}

// ---------------------------------------------------------------------------
extern "C" void kernel_launch(void* const* d_in, const int* in_sizes, int n_in,
                              void* d_out, int out_size, void* d_ws, size_t ws_size,
                              hipStream_t stream)
{
  const int*   item_id  = (const int*)  d_in[0];
  const int*   cat_id   = (const int*)  d_in[1];
  const int*   src_in   = (const int*)  d_in[2];
  const int*   dst_in   = (const int*)  d_in[3];
  const float* emb_item = (const float*)d_in[4];
  const float* emb_cat  = (const float*)d_in[5];
  const float* W1r = (const float*)d_in[6];
  const float* W1n = (const float*)d_in[7];
  const float* b1  = (const float*)d_in[8];
  const float* p1  = (const float*)d_in[9];
  const float* W2r = (const float*)d_in[10];
  const float* W2n = (const float*)d_in[11];
  const float* b2  = (const float*)d_in[12];
  const float* p2  = (const float*)d_in[13];
  const float* W3r = (const float*)d_in[14];
  const float* W3n = (const float*)d_in[15];
  const float* b3  = (const float*)d_in[16];
  const float* p3  = (const float*)d_in[17];
  const float* fc1_W = (const float*)d_in[18];
  const float* fc1_b = (const float*)d_in[19];
  const float* bn1_g = (const float*)d_in[20];
  const float* bn1_b = (const float*)d_in[21];
  const float* fc2_W = (const float*)d_in[22];
  const float* fc2_b = (const float*)d_in[23];
  const float* bn2_g = (const float*)d_in[24];
  const float* bn2_b = (const float*)d_in[25];
  float* out = (float*)d_out;

  const int TN = TOTAL_NODES;
  const int E  = E_TOTAL;
  const int k1 = 461, k2 = 415, k3 = 374;
  const int M1 = TN;              // 131072
  const int M2 = NUM_GRAPHS * k1; // 118016
  const int M3 = NUM_GRAPHS * k2; // 106240
  const int M4 = NUM_GRAPHS * k3; // 95744

  char* ws = (char*)d_ws;
  size_t off = 0;
  auto carve = [&](size_t bytes) { char* p = ws + off; off += align256(bytes); return p; };
  float* buf0   = (float*)carve((size_t)TN * FDIM * 4);
  float* buf1   = (float*)carve((size_t)TN * FDIM * 4);
  float* score  = (float*)carve((size_t)TN * 4);
  int*   sel    = (int*)  carve((size_t)TN * 4);
  int*   mapping= (int*)  carve((size_t)TN * 4);
  int*   srcw   = (int*)  carve((size_t)E * 4);
  int*   dstw   = (int*)  carve((size_t)E * 4);
  int*   counts = (int*)  carve((size_t)TN * 4);
  int*   offs   = (int*)  carve((size_t)TN * 4);
  int*   cursor = (int*)  carve((size_t)TN * 4);
  int*   slots  = (int*)  carve((size_t)E * 4);
  float* g      = (float*)carve(256 * 256 * 4);
  float* h1     = (float*)carve(256 * 128 * 4);
  float* h2     = (float*)carve(256 * 64 * 4);
  float* nrm    = (float*)carve(256);
  if (off > ws_size) return;

  dim3 b256(256);
  auto blocks = [](long long work, int bs) { return dim3((unsigned)((work + bs - 1) / bs)); };

  auto aggregate = [&](const float* x, const int* s, const int* d, float* agg,
                       int n_per_g, int M) {
    hipMemsetAsync(counts, 0, (size_t)M * 4, stream);
    csr_count_k<<<blocks(E, 256), b256, 0, stream>>>(d, counts, E);
    csr_scan_k<<<dim3(NUM_GRAPHS), dim3(512), 0, stream>>>(counts, n_per_g, offs, cursor);
    csr_scatter_k<<<blocks(E, 256), b256, 0, stream>>>(s, d, cursor, slots, E);
    gather_lds_k<<<dim3(NUM_GRAPHS, 4), b256, 0, stream>>>(x, slots, offs, counts, agg, n_per_g);
  };

  hipMemsetAsync(g, 0, 256 * 256 * 4, stream);

  gather_embed_k<<<blocks((long long)TN * 32, 256), b256, 0, stream>>>(
      item_id, cat_id, emb_item, emb_cat, buf0, TN);

  // ================= stage 1 (x = buf0) =================
  pnorm_k<<<dim3(1), dim3(128), 0, stream>>>(p1, nrm);
  aggregate(buf0, src_in, dst_in, buf1, NODES_PER_G, M1);
  conv_mfma_k<<<dim3(M1 / 128), b256, 0, stream>>>(
      buf0, W1r, buf1, W1n, b1, p1, nrm, buf0, score, M1);
  topk_sort_k<<<dim3(NUM_GRAPHS), dim3(512), 0, stream>>>(score, NODES_PER_G, k1, sel, mapping);
  pool_readout_k<<<dim3(NUM_GRAPHS, 4), b256, 0, stream>>>(buf0, score, sel, buf1, g, k1);
  edge_remap_k<<<blocks(E, 256), b256, 0, stream>>>(src_in, dst_in, mapping, srcw, dstw, E);

  // ================= stage 2 (x = buf1) =================
  pnorm_k<<<dim3(1), dim3(128), 0, stream>>>(p2, nrm);
  aggregate(buf1, srcw, dstw, buf0, k1, M2);
  conv_mfma_k<<<dim3(M2 / 128), b256, 0, stream>>>(
      buf1, W2r, buf0, W2n, b2, p2, nrm, buf1, score, M2);
  topk_sort_k<<<dim3(NUM_GRAPHS), dim3(512), 0, stream>>>(score, k1, k2, sel, mapping);
  pool_readout_k<<<dim3(NUM_GRAPHS, 4), b256, 0, stream>>>(buf1, score, sel, buf0, g, k2);
  edge_remap_k<<<blocks(E, 256), b256, 0, stream>>>(srcw, dstw, mapping, srcw, dstw, E);

  // ================= stage 3 (x = buf0) =================
  pnorm_k<<<dim3(1), dim3(128), 0, stream>>>(p3, nrm);
  aggregate(buf0, srcw, dstw, buf1, k2, M3);
  conv_mfma_k<<<dim3(M3 / 128), b256, 0, stream>>>(
      buf0, W3r, buf1, W3n, b3, p3, nrm, buf0, score, M3);
  topk_sort_k<<<dim3(NUM_GRAPHS), dim3(512), 0, stream>>>(score, k2, k3, sel, mapping);
  pool_readout_k<<<dim3(NUM_GRAPHS, 4), b256, 0, stream>>>(buf0, score, sel, buf1, g, k3);

  // ================= head =================
  fc_k<<<blocks(256 * 128, 256), b256, 0, stream>>>(g, fc1_W, fc1_b, h1, 256, 256, 128);
  bn_relu_k<<<dim3(128), b256, 0, stream>>>(h1, bn1_g, bn1_b, 128);
  fc_k<<<blocks(256 * 64, 256), b256, 0, stream>>>(h1, fc2_W, fc2_b, h2, 256, 128, 64);
  bn_relu_k<<<dim3(64), b256, 0, stream>>>(h2, bn2_g, bn2_b, 64);

  final_k<<<blocks(TN, 256), b256, 0, stream>>>(item_id, emb_item, h2, out, TN);
}

// Round 5
// 548.754 us; speedup vs baseline: 5.6618x; 1.4140x over previous
//
#include <hip/hip_runtime.h>
#include <hip/hip_bf16.h>
#include <math.h>

// ---------------------------------------------------------------------------
// NetNode: 3x (GraphConv -> TopKPooling -> readout) + FC/BN head + per-node dot
// B=256, N=512, E=2048/graph, F=128, EMB=64. k1=461, k2=415, k3=374.
// R5: (1) conv v3: W pre-split to bf16 hi/lo fragment layout (wprep), A loaded
//     global->reg (no A-LDS), LDS only 36KB for W-half. (2) pooled x never
//     materialized: consumers read x_prev[sel]*gates on the fly. (3) CSR build
//     fused into one per-graph kernel (remap+hist+scan+scatter).
// ---------------------------------------------------------------------------

#define TOTAL_NODES 131072   // B*N
#define NUM_GRAPHS  256
#define NODES_PER_G 512
#define E_TOTAL     524288   // B*E
#define EPG         2048     // edges per graph (slot capacity)
#define FDIM        128
#define EMBD        64

typedef __bf16 bf16x8 __attribute__((ext_vector_type(8)));
typedef float  f32x4  __attribute__((ext_vector_type(4)));

static __device__ __forceinline__ f32x4 mfma16(bf16x8 a, bf16x8 b, f32x4 c) {
  return __builtin_amdgcn_mfma_f32_16x16x32_bf16(a, b, c, 0, 0, 0);
}

static inline size_t align256(size_t x) { return (x + 255) & ~size_t(255); }

// ---------------- gather embeddings
__global__ __launch_bounds__(256) void gather_embed_k(
    const int* __restrict__ item_id, const int* __restrict__ cat_id,
    const float* __restrict__ emb_item, const float* __restrict__ emb_cat,
    float* __restrict__ x, int total)
{
  int i = blockIdx.x * 256 + threadIdx.x;
  int node = i >> 5, part = i & 31;
  if (node >= total) return;
  float4 v;
  if (part < 16) {
    v = *(const float4*)&emb_item[(size_t)item_id[node] * EMBD + part * 4];
  } else {
    v = *(const float4*)&emb_cat[(size_t)cat_id[node] * EMBD + (part - 16) * 4];
  }
  *(float4*)&x[(size_t)node * FDIM + part * 4] = v;
}

// ---------------- W pre-split: W[k][n] fp32 -> Wh/Wl[n][k] bf16 (hi/lo)
// grid (64, 6): 6 matrices
__global__ __launch_bounds__(256) void wprep_k(
    const float* __restrict__ w0, const float* __restrict__ w1,
    const float* __restrict__ w2, const float* __restrict__ w3,
    const float* __restrict__ w4, const float* __restrict__ w5,
    __bf16* __restrict__ wout)   // wout[mat][hi=0/lo=1][n*128+k]
{
  const float* ws[6] = {w0, w1, w2, w3, w4, w5};
  int mat = blockIdx.y;
  int idx = blockIdx.x * 256 + threadIdx.x;   // 0..16383
  int n = idx >> 7, k = idx & 127;
  float v = ws[mat][k * FDIM + n];
  __bf16 h = (__bf16)v;
  __bf16 l = (__bf16)(v - (float)h);
  __bf16* base = wout + (size_t)mat * 2 * 16384;
  base[idx] = h;
  base[16384 + idx] = l;
}

// ---------------- fused CSR build (+remap): one block per graph, 512 threads
// Writes: src_out/dst_out (remapped global new ids, -1 invalid), slots (LOCAL
// src ids), counts/offs (per global new id).
__global__ __launch_bounds__(512) void csr_build_k(
    const int* __restrict__ src_in, const int* __restrict__ dst_in,
    const int* __restrict__ mapping,   // null for stage 1 (identity)
    int* __restrict__ src_out, int* __restrict__ dst_out,
    int* __restrict__ slots, int* __restrict__ counts, int* __restrict__ offs,
    int n_new)
{
  __shared__ int hist[512];
  __shared__ int scan[512];
  __shared__ int cursor[512];
  const int g = blockIdx.x, t = threadIdx.x;
  const int ebase = g * EPG;
  const int nbase = g * n_new;
  hist[t] = 0;
  __syncthreads();
  int ls[4], ld[4];
#pragma unroll
  for (int i = 0; i < 4; ++i) {
    int e = ebase + t + i * 512;
    int s = src_in[e], d = dst_in[e];
    if (mapping) {
      s = (s >= 0) ? mapping[s] : -1;
      d = (d >= 0) ? mapping[d] : -1;
      if (s < 0 || d < 0) { s = -1; d = -1; }
    }
    src_out[e] = s; dst_out[e] = d;
    ls[i] = (s >= 0) ? (s - nbase) : -1;
    ld[i] = (d >= 0) ? (d - nbase) : -1;
    if (ld[i] >= 0) atomicAdd(&hist[ld[i]], 1);
  }
  __syncthreads();
  int v = (t < n_new) ? hist[t] : 0;
  scan[t] = v;
  __syncthreads();
  for (int dlt = 1; dlt < 512; dlt <<= 1) {
    int add = (t >= dlt) ? scan[t - dlt] : 0;
    __syncthreads();
    scan[t] += add;
    __syncthreads();
  }
  if (t < n_new) {
    int excl = scan[t] - v;
    counts[nbase + t] = v;
    offs[nbase + t] = g * EPG + excl;
    cursor[t] = excl;
  }
  __syncthreads();
#pragma unroll
  for (int i = 0; i < 4; ++i) {
    if (ld[i] >= 0) {
      int pos = atomicAdd(&cursor[ld[i]], 1);
      slots[ebase + pos] = ls[i];
    }
  }
}

// ---------------- LDS-staged aggregation with on-the-fly pooling
// grid (NUM_GRAPHS, 4); stages pooled x rows (chunk of 32 feats) in LDS,
// then CSR-gathers. agg written dense (all n_per_g rows per graph).
#define GCH  32
#define GPAD 36
__global__ __launch_bounds__(256) void gather_lds_k(
    const float* __restrict__ x, const int* __restrict__ sel,
    const float* __restrict__ gates, const int* __restrict__ slots,
    const int* __restrict__ off, const int* __restrict__ counts,
    float* __restrict__ agg, int n_per_g)
{
  __shared__ float xs[NODES_PER_G * GPAD];
  const int g = blockIdx.x, ch = blockIdx.y;
  const int tid = threadIdx.x;
  const int c0 = ch * GCH;
  const int rowbase = g * n_per_g;
  const int nv4 = n_per_g * 8;
  for (int v = tid; v < nv4; v += 256) {
    int r = v >> 3, c4 = (v & 7) * 4;
    int srow; float gt;
    if (sel) { srow = sel[rowbase + r]; gt = gates[rowbase + r]; }
    else     { srow = rowbase + r;      gt = 1.0f; }
    float4 t = *(const float4*)&x[(size_t)srow * FDIM + c0 + c4];
    t.x *= gt; t.y *= gt; t.z *= gt; t.w *= gt;
    *(float4*)&xs[r * GPAD + c4] = t;
  }
  __syncthreads();
  const int nlane = tid & 7;
  const int nslot = tid >> 3;
  for (int n = nslot; n < n_per_g; n += 32) {
    int gn = rowbase + n;
    int deg = counts[gn];
    int base = off[gn];
    float4 a = make_float4(0.f, 0.f, 0.f, 0.f);
    for (int d = 0; d < deg; ++d) {
      int s = slots[base + d];          // local id
      float4 v = *(const float4*)&xs[s * GPAD + nlane * 4];
      a.x += v.x; a.y += v.y; a.z += v.z; a.w += v.w;
    }
    *(float4*)&agg[(size_t)gn * FDIM + c0 + nlane * 4] = a;
  }
}

// ---------------- conv v3: C[M,128] = relu(A1p@W1 + A2@W2 + b), bf16x3 MFMA.
// A1p row r = Asrc[sel[r]] * gates[r] (or dense if sel==null). A loaded
// global->reg. W pre-split bf16 hi/lo in [n][k] layout, staged per-half in LDS.
// Fused score epilogue. In-place safe: C may alias A2 (and A1 when sel==null) --
// blocks read only their own 128 rows before writing them.
__global__ __launch_bounds__(256) void conv_mfma_k(
    const float* __restrict__ Asrc, const int* __restrict__ sel,
    const float* __restrict__ gates,
    const __bf16* __restrict__ W1hl,    // [hi 16384][lo 16384]
    const float* __restrict__ A2,
    const __bf16* __restrict__ W2hl,
    const float* __restrict__ bias, const float* __restrict__ p,
    const float* __restrict__ nrm, float* __restrict__ C,
    float* __restrict__ score, int M)
{
  __shared__ __bf16 Wh[128 * 72];   // 18 KB
  __shared__ __bf16 Wl[128 * 72];   // 18 KB

  const int tid  = threadIdx.x;
  const int lane = tid & 63;
  const int w    = tid >> 6;
  const int row0 = blockIdx.x * 128;
  const int l15  = lane & 15;
  const int lg   = lane >> 4;

  f32x4 acc[2][8];
#pragma unroll
  for (int rf = 0; rf < 2; ++rf)
#pragma unroll
    for (int cf = 0; cf < 8; ++cf) acc[rf][cf] = (f32x4){0.f, 0.f, 0.f, 0.f};

  const int grow0 = row0 + w * 32 + l15;
  const int grow1 = grow0 + 16;

  for (int pass = 0; pass < 2; ++pass) {
    const float* __restrict__ A = pass ? A2 : Asrc;
    const __bf16* __restrict__ Whl = pass ? W2hl : W1hl;
    const bool use_sel = (pass == 0) && (sel != nullptr);
    int srow0 = use_sel ? sel[grow0] : grow0;
    int srow1 = use_sel ? sel[grow1] : grow1;
    float gt0 = use_sel ? gates[grow0] : 1.0f;
    float gt1 = use_sel ? gates[grow1] : 1.0f;

    for (int half = 0; half < 2; ++half) {
      const int k0 = half * 64;
      __syncthreads();   // protect prior half's LDS reads
      // stage W-half: 128 cols x 64 k, hi+lo (no conversion math)
      for (int v = tid; v < 1024; v += 256) {
        int c = v >> 3, chn = (v & 7) * 8;
        *(bf16x8*)&Wh[c * 72 + chn] = *(const bf16x8*)&Whl[c * 128 + k0 + chn];
        *(bf16x8*)&Wl[c * 72 + chn] = *(const bf16x8*)&Whl[16384 + c * 128 + k0 + chn];
      }
      __syncthreads();

      // A fragments: global -> reg, gate, hi/lo split
      bf16x8 ah[2][2], al[2][2];
#pragma unroll
      for (int rf = 0; rf < 2; ++rf) {
        int srow = rf ? srow1 : srow0;
        float gt = rf ? gt1 : gt0;
#pragma unroll
        for (int kc = 0; kc < 2; ++kc) {
          const float* ap = &A[(size_t)srow * FDIM + k0 + kc * 32 + lg * 8];
          float4 u0 = *(const float4*)ap;
          float4 u1 = *(const float4*)(ap + 4);
          float av[8] = {u0.x, u0.y, u0.z, u0.w, u1.x, u1.y, u1.z, u1.w};
#pragma unroll
          for (int j = 0; j < 8; ++j) {
            float vv = av[j] * gt;
            __bf16 h = (__bf16)vv;
            ah[rf][kc][j] = h;
            al[rf][kc][j] = (__bf16)(vv - (float)h);
          }
        }
      }
#pragma unroll
      for (int kc = 0; kc < 2; ++kc) {
        const int koff = kc * 32 + lg * 8;
#pragma unroll
        for (int cf = 0; cf < 8; ++cf) {
          const int bo = (cf * 16 + l15) * 72 + koff;
          bf16x8 bh = *(const bf16x8*)&Wh[bo];
          bf16x8 bl = *(const bf16x8*)&Wl[bo];
          acc[0][cf] = mfma16(ah[0][kc], bh, acc[0][cf]);
          acc[0][cf] = mfma16(ah[0][kc], bl, acc[0][cf]);
          acc[0][cf] = mfma16(al[0][kc], bh, acc[0][cf]);
          acc[1][cf] = mfma16(ah[1][kc], bh, acc[1][cf]);
          acc[1][cf] = mfma16(ah[1][kc], bl, acc[1][cf]);
          acc[1][cf] = mfma16(al[1][kc], bh, acc[1][cf]);
        }
      }
    }
  }

  // epilogue: bias+relu, store, fused normalized score
  const float nv = nrm[0];
  float bv[8], pv[8];
#pragma unroll
  for (int cf = 0; cf < 8; ++cf) {
    int col = cf * 16 + l15;
    bv[cf] = bias[col];
    pv[cf] = p[col];
  }
#pragma unroll
  for (int rf = 0; rf < 2; ++rf) {
#pragma unroll
    for (int j = 0; j < 4; ++j) {
      int row = row0 + w * 32 + rf * 16 + lg * 4 + j;
      float* crow = &C[(size_t)row * FDIM];
      float rsv = 0.f;
#pragma unroll
      for (int cf = 0; cf < 8; ++cf) {
        float val = acc[rf][cf][j] + bv[cf];
        val = fmaxf(val, 0.f);
        crow[cf * 16 + l15] = val;
        rsv += val * pv[cf];
      }
      rsv += __shfl_xor(rsv, 1, 16);
      rsv += __shfl_xor(rsv, 2, 16);
      rsv += __shfl_xor(rsv, 4, 16);
      rsv += __shfl_xor(rsv, 8, 16);
      if (l15 == 0) score[row] = rsv / nv;
    }
  }
}

// ---------------- ||p||
__global__ __launch_bounds__(128) void pnorm_k(const float* __restrict__ p,
                                               float* __restrict__ nrm)
{
  __shared__ float ss[128];
  int t = threadIdx.x;
  float v = p[t];
  ss[t] = v * v;
  __syncthreads();
  for (int s = 64; s > 0; s >>= 1) {
    if (t < s) ss[t] += ss[t + s];
    __syncthreads();
  }
  if (t == 0) nrm[0] = sqrtf(ss[0]);
}

// ---------------- per-graph top-k via bitonic sort; emits sel, mapping, gates
__global__ __launch_bounds__(512) void topk_sort_k(
    const float* __restrict__ score, int n_old, int k_new,
    int* __restrict__ sel, int* __restrict__ mapping, float* __restrict__ gates)
{
  __shared__ float sv[512];
  __shared__ int   si[512];
  int b = blockIdx.x, t = threadIdx.x;
  sv[t] = (t < n_old) ? -score[(size_t)b * n_old + t] : 3.0e38f;
  si[t] = t;
  __syncthreads();
  for (int k = 2; k <= 512; k <<= 1) {
    for (int j = k >> 1; j > 0; j >>= 1) {
      int ixj = t ^ j;
      if (ixj > t) {
        bool up = ((t & k) == 0);
        float a = sv[t], c = sv[ixj];
        if ((a > c) == up) {
          sv[t] = c; sv[ixj] = a;
          int tmp = si[t]; si[t] = si[ixj]; si[ixj] = tmp;
        }
      }
      __syncthreads();
    }
  }
  if (t < n_old) {
    int old_g = b * n_old + si[t];
    if (t < k_new) {
      sel[b * k_new + t] = old_g;
      mapping[old_g] = b * k_new + t;
      gates[b * k_new + t] = tanhf(-sv[t]);
    } else {
      mapping[old_g] = -1;
    }
  }
}

// ---------------- readout over pooled rows (no materialization)
// grid (NUM_GRAPHS, 4); 32 slots x 8 float4-lanes
__global__ __launch_bounds__(256) void readout_k(
    const float* __restrict__ x, const int* __restrict__ sel,
    const float* __restrict__ gates, float* __restrict__ g, int k)
{
  __shared__ float lmx[32 * 36];
  __shared__ float lsm[32 * 36];
  const int b = blockIdx.x, ch = blockIdx.y;
  const int c0 = ch * 32;
  const int tid = threadIdx.x;
  const int lane = tid & 7;
  const int slot = tid >> 3;
  float4 mx = make_float4(-3.0e38f, -3.0e38f, -3.0e38f, -3.0e38f);
  float4 sm = make_float4(0.f, 0.f, 0.f, 0.f);
  for (int n = slot; n < k; n += 32) {
    int node = b * k + n;
    int old = sel[node];
    float gate = gates[node];
    float4 v = *(const float4*)&x[(size_t)old * FDIM + c0 + lane * 4];
    v.x *= gate; v.y *= gate; v.z *= gate; v.w *= gate;
    mx.x = fmaxf(mx.x, v.x); mx.y = fmaxf(mx.y, v.y);
    mx.z = fmaxf(mx.z, v.z); mx.w = fmaxf(mx.w, v.w);
    sm.x += v.x; sm.y += v.y; sm.z += v.z; sm.w += v.w;
  }
  float* pm = &lmx[slot * 36 + lane * 4];
  float* ps = &lsm[slot * 36 + lane * 4];
  pm[0] = mx.x; pm[1] = mx.y; pm[2] = mx.z; pm[3] = mx.w;
  ps[0] = sm.x; ps[1] = sm.y; ps[2] = sm.z; ps[3] = sm.w;
  __syncthreads();
  for (int s = 16; s > 0; s >>= 1) {
    if (slot < s) {
#pragma unroll
      for (int j = 0; j < 4; ++j) {
        int a = slot * 36 + lane * 4 + j;
        int bb = (slot + s) * 36 + lane * 4 + j;
        lmx[a] = fmaxf(lmx[a], lmx[bb]);
        lsm[a] += lsm[bb];
      }
    }
    __syncthreads();
  }
  if (slot == 0) {
    float inv_k = 1.f / (float)k;
#pragma unroll
    for (int j = 0; j < 4; ++j) {
      int c = c0 + lane * 4 + j;
      g[b * 256 + c]       += lmx[lane * 4 + j];
      g[b * 256 + 128 + c] += lsm[lane * 4 + j] * inv_k;
    }
  }
}

// ---------------- fc
__global__ __launch_bounds__(256) void fc_k(
    const float* __restrict__ in, const float* __restrict__ W,
    const float* __restrict__ bias, float* __restrict__ out,
    int rows, int K, int C)
{
  int idx = blockIdx.x * 256 + threadIdx.x;
  if (idx >= rows * C) return;
  int row = idx / C, c = idx % C;
  float s = bias[c];
  const float* grow = &in[(size_t)row * K];
  for (int t = 0; t < K; ++t) s += grow[t] * W[(size_t)t * C + c];
  out[idx] = s;
}

// ---------------- BatchNorm (training stats over 256 rows) + relu
__global__ __launch_bounds__(256) void bn_relu_k(
    float* __restrict__ h, const float* __restrict__ gamma,
    const float* __restrict__ beta, int C)
{
  __shared__ float ssum[256], ssq[256];
  int c = blockIdx.x, r = threadIdx.x;
  float v = h[(size_t)r * C + c];
  ssum[r] = v; ssq[r] = v * v;
  __syncthreads();
  for (int s = 128; s > 0; s >>= 1) {
    if (r < s) { ssum[r] += ssum[r + s]; ssq[r] += ssq[r + s]; }
    __syncthreads();
  }
  float m = ssum[0] * (1.f / 256.f);
  float var = ssq[0] * (1.f / 256.f) - m * m;
  float o = gamma[c] * (v - m) * rsqrtf(var + 1e-5f) + beta[c];
  h[(size_t)r * C + c] = fmaxf(o, 0.f);
}

// ---------------- out[nid] = sigmoid(dot(emb_item[item_id[nid]], g2[graph]))
__global__ __launch_bounds__(256) void final_k(
    const int* __restrict__ item_id, const float* __restrict__ emb_item,
    const float* __restrict__ g2, float* __restrict__ out, int total)
{
  int nid = blockIdx.x * 256 + threadIdx.x;
  if (nid >= total) return;
  int b = nid >> 9;
  const float* e = &emb_item[(size_t)item_id[nid] * EMBD];
  const float* gg = &g2[(size_t)b * 64];
  float s = 0.f;
#pragma unroll
  for (int j = 0; j < 64; j += 4) {
    float4 a = *(const float4*)&e[j];
    float4 c = *(const float4*)&gg[j];
    s += a.x * c.x + a.y * c.y + a.z * c.z + a.w * c.w;
  }
  out[nid] = 1.f / (1.f + expf(-s));
}

// ---------------------------------------------------------------------------
extern "C" void kernel_launch(void* const* d_in, const int* in_sizes, int n_in,
                              void* d_out, int out_size, void* d_ws, size_t ws_size,
                              hipStream_t stream)
{
  const int*   item_id  = (const int*)  d_in[0];
  const int*   cat_id   = (const int*)  d_in[1];
  const int*   src_in   = (const int*)  d_in[2];
  const int*   dst_in   = (const int*)  d_in[3];
  const float* emb_item = (const float*)d_in[4];
  const float* emb_cat  = (const float*)d_in[5];
  const float* W1r = (const float*)d_in[6];
  const float* W1n = (const float*)d_in[7];
  const float* b1  = (const float*)d_in[8];
  const float* p1  = (const float*)d_in[9];
  const float* W2r = (const float*)d_in[10];
  const float* W2n = (const float*)d_in[11];
  const float* b2  = (const float*)d_in[12];
  const float* p2  = (const float*)d_in[13];
  const float* W3r = (const float*)d_in[14];
  const float* W3n = (const float*)d_in[15];
  const float* b3  = (const float*)d_in[16];
  const float* p3  = (const float*)d_in[17];
  const float* fc1_W = (const float*)d_in[18];
  const float* fc1_b = (const float*)d_in[19];
  const float* bn1_g = (const float*)d_in[20];
  const float* bn1_b = (const float*)d_in[21];
  const float* fc2_W = (const float*)d_in[22];
  const float* fc2_b = (const float*)d_in[23];
  const float* bn2_g = (const float*)d_in[24];
  const float* bn2_b = (const float*)d_in[25];
  float* out = (float*)d_out;

  const int TN = TOTAL_NODES;
  const int E  = E_TOTAL;
  const int k1 = 461, k2 = 415, k3 = 374;
  const int M1 = TN;              // 131072
  const int M2 = NUM_GRAPHS * k1; // 118016
  const int M3 = NUM_GRAPHS * k2; // 106240

  char* ws = (char*)d_ws;
  size_t off = 0;
  auto carve = [&](size_t bytes) { char* p = ws + off; off += align256(bytes); return p; };
  float*  buf0   = (float*) carve((size_t)TN * FDIM * 4);
  float*  buf1   = (float*) carve((size_t)TN * FDIM * 4);
  float*  score  = (float*) carve((size_t)TN * 4);
  int*    sel    = (int*)   carve((size_t)TN * 4);
  int*    mapping= (int*)   carve((size_t)TN * 4);
  float*  gates  = (float*) carve((size_t)TN * 4);
  int*    srcw   = (int*)   carve((size_t)E * 4);
  int*    dstw   = (int*)   carve((size_t)E * 4);
  int*    counts = (int*)   carve((size_t)TN * 4);
  int*    offs   = (int*)   carve((size_t)TN * 4);
  int*    slots  = (int*)   carve((size_t)E * 4);
  __bf16* wbuf   = (__bf16*)carve(6 * 2 * 16384 * 2);
  float*  g      = (float*) carve(256 * 256 * 4);
  float*  h1     = (float*) carve(256 * 128 * 4);
  float*  h2     = (float*) carve(256 * 64 * 4);
  float*  nrm    = (float*) carve(256);
  if (off > ws_size) return;

  dim3 b256(256);
  auto blocks = [](long long work, int bs) { return dim3((unsigned)((work + bs - 1) / bs)); };

  const __bf16* W1r_hl = wbuf + 0 * 2 * 16384;
  const __bf16* W1n_hl = wbuf + 1 * 2 * 16384;
  const __bf16* W2r_hl = wbuf + 2 * 2 * 16384;
  const __bf16* W2n_hl = wbuf + 3 * 2 * 16384;
  const __bf16* W3r_hl = wbuf + 4 * 2 * 16384;
  const __bf16* W3n_hl = wbuf + 5 * 2 * 16384;

  hipMemsetAsync(g, 0, 256 * 256 * 4, stream);
  wprep_k<<<dim3(64, 6), b256, 0, stream>>>(W1r, W1n, W2r, W2n, W3r, W3n, wbuf);
  gather_embed_k<<<blocks((long long)TN * 32, 256), b256, 0, stream>>>(
      item_id, cat_id, emb_item, emb_cat, buf0, TN);

  // ================= stage 1 (x0 = buf0, dense) =================
  pnorm_k<<<dim3(1), dim3(128), 0, stream>>>(p1, nrm);
  csr_build_k<<<dim3(NUM_GRAPHS), dim3(512), 0, stream>>>(
      src_in, dst_in, nullptr, srcw, dstw, slots, counts, offs, NODES_PER_G);
  gather_lds_k<<<dim3(NUM_GRAPHS, 4), b256, 0, stream>>>(
      buf0, nullptr, nullptr, slots, offs, counts, buf1, NODES_PER_G);
  conv_mfma_k<<<dim3(M1 / 128), b256, 0, stream>>>(
      buf0, nullptr, nullptr, W1r_hl, buf1, W1n_hl, b1, p1, nrm, buf0, score, M1);
  topk_sort_k<<<dim3(NUM_GRAPHS), dim3(512), 0, stream>>>(
      score, NODES_PER_G, k1, sel, mapping, gates);
  readout_k<<<dim3(NUM_GRAPHS, 4), b256, 0, stream>>>(buf0, sel, gates, g, k1);

  // ================= stage 2 (x1 = buf0 via sel/gates) =================
  pnorm_k<<<dim3(1), dim3(128), 0, stream>>>(p2, nrm);
  csr_build_k<<<dim3(NUM_GRAPHS), dim3(512), 0, stream>>>(
      srcw, dstw, mapping, srcw, dstw, slots, counts, offs, k1);
  gather_lds_k<<<dim3(NUM_GRAPHS, 4), b256, 0, stream>>>(
      buf0, sel, gates, slots, offs, counts, buf1, k1);
  conv_mfma_k<<<dim3(M2 / 128), b256, 0, stream>>>(
      buf0, sel, gates, W2r_hl, buf1, W2n_hl, b2, p2, nrm, buf1, score, M2);
  topk_sort_k<<<dim3(NUM_GRAPHS), dim3(512), 0, stream>>>(
      score, k1, k2, sel, mapping, gates);
  readout_k<<<dim3(NUM_GRAPHS, 4), b256, 0, stream>>>(buf1, sel, gates, g, k2);

  // ================= stage 3 (x2 = buf1 via sel/gates) =================
  pnorm_k<<<dim3(1), dim3(128), 0, stream>>>(p3, nrm);
  csr_build_k<<<dim3(NUM_GRAPHS), dim3(512), 0, stream>>>(
      srcw, dstw, mapping, srcw, dstw, slots, counts, offs, k2);
  gather_lds_k<<<dim3(NUM_GRAPHS, 4), b256, 0, stream>>>(
      buf1, sel, gates, slots, offs, counts, buf0, k2);
  conv_mfma_k<<<dim3(M3 / 128), b256, 0, stream>>>(
      buf1, sel, gates, W3r_hl, buf0, W3n_hl, b3, p3, nrm, buf0, score, M3);
  topk_sort_k<<<dim3(NUM_GRAPHS), dim3(512), 0, stream>>>(
      score, k2, k3, sel, mapping, gates);
  readout_k<<<dim3(NUM_GRAPHS, 4), b256, 0, stream>>>(buf0, sel, gates, g, k3);

  // ================= head =================
  fc_k<<<blocks(256 * 128, 256), b256, 0, stream>>>(g, fc1_W, fc1_b, h1, 256, 256, 128);
  bn_relu_k<<<dim3(128), b256, 0, stream>>>(h1, bn1_g, bn1_b, 128);
  fc_k<<<blocks(256 * 64, 256), b256, 0, stream>>>(h1, fc2_W, fc2_b, h2, 256, 128, 64);
  bn_relu_k<<<dim3(64), b256, 0, stream>>>(h2, bn2_g, bn2_b, 64);

  final_k<<<blocks(TN, 256), b256, 0, stream>>>(item_id, emb_item, h2, out, TN);
}

// Round 6
// 473.545 us; speedup vs baseline: 6.5610x; 1.1588x over previous
//
#include <hip/hip_runtime.h>
#include <hip/hip_bf16.h>
#include <math.h>

// ---------------------------------------------------------------------------
// NetNode: 3x (GraphConv -> TopKPooling -> readout) + FC/BN head + per-node dot
// B=256, N=512, E=2048/graph, F=128, EMB=64. k1=461, k2=415, k3=374.
// R6: head rewritten -- fc_k was 89us each (rolled K-loop, serial latency).
//     head1_k/head2_k fuse fc+bn+relu with unrolled K and in-block BN stats.
//     pnorm x3 merged into one pnorm3_k.
// ---------------------------------------------------------------------------

#define TOTAL_NODES 131072   // B*N
#define NUM_GRAPHS  256
#define NODES_PER_G 512
#define E_TOTAL     524288   // B*E
#define EPG         2048     // edges per graph (slot capacity)
#define FDIM        128
#define EMBD        64

typedef __bf16 bf16x8 __attribute__((ext_vector_type(8)));
typedef float  f32x4  __attribute__((ext_vector_type(4)));

static __device__ __forceinline__ f32x4 mfma16(bf16x8 a, bf16x8 b, f32x4 c) {
  return __builtin_amdgcn_mfma_f32_16x16x32_bf16(a, b, c, 0, 0, 0);
}

static inline size_t align256(size_t x) { return (x + 255) & ~size_t(255); }

// ---------------- gather embeddings
__global__ __launch_bounds__(256) void gather_embed_k(
    const int* __restrict__ item_id, const int* __restrict__ cat_id,
    const float* __restrict__ emb_item, const float* __restrict__ emb_cat,
    float* __restrict__ x, int total)
{
  int i = blockIdx.x * 256 + threadIdx.x;
  int node = i >> 5, part = i & 31;
  if (node >= total) return;
  float4 v;
  if (part < 16) {
    v = *(const float4*)&emb_item[(size_t)item_id[node] * EMBD + part * 4];
  } else {
    v = *(const float4*)&emb_cat[(size_t)cat_id[node] * EMBD + (part - 16) * 4];
  }
  *(float4*)&x[(size_t)node * FDIM + part * 4] = v;
}

// ---------------- W pre-split: W[k][n] fp32 -> Wh/Wl[n][k] bf16 (hi/lo)
__global__ __launch_bounds__(256) void wprep_k(
    const float* __restrict__ w0, const float* __restrict__ w1,
    const float* __restrict__ w2, const float* __restrict__ w3,
    const float* __restrict__ w4, const float* __restrict__ w5,
    __bf16* __restrict__ wout)
{
  const float* ws[6] = {w0, w1, w2, w3, w4, w5};
  int mat = blockIdx.y;
  int idx = blockIdx.x * 256 + threadIdx.x;   // 0..16383
  int n = idx >> 7, k = idx & 127;
  float v = ws[mat][k * FDIM + n];
  __bf16 h = (__bf16)v;
  __bf16 l = (__bf16)(v - (float)h);
  __bf16* base = wout + (size_t)mat * 2 * 16384;
  base[idx] = h;
  base[16384 + idx] = l;
}

// ---------------- norms of p1,p2,p3 in one launch
__global__ __launch_bounds__(128) void pnorm3_k(
    const float* __restrict__ p1, const float* __restrict__ p2,
    const float* __restrict__ p3, float* __restrict__ nrm)
{
  __shared__ float ss[128];
  const float* ps[3] = {p1, p2, p3};
  int t = threadIdx.x;
  for (int m = 0; m < 3; ++m) {
    float v = ps[m][t];
    ss[t] = v * v;
    __syncthreads();
    for (int s = 64; s > 0; s >>= 1) {
      if (t < s) ss[t] += ss[t + s];
      __syncthreads();
    }
    if (t == 0) nrm[m] = sqrtf(ss[0]);
    __syncthreads();
  }
}

// ---------------- fused CSR build (+remap): one block per graph
__global__ __launch_bounds__(512) void csr_build_k(
    const int* __restrict__ src_in, const int* __restrict__ dst_in,
    const int* __restrict__ mapping,
    int* __restrict__ src_out, int* __restrict__ dst_out,
    int* __restrict__ slots, int* __restrict__ counts, int* __restrict__ offs,
    int n_new)
{
  __shared__ int hist[512];
  __shared__ int scan[512];
  __shared__ int cursor[512];
  const int g = blockIdx.x, t = threadIdx.x;
  const int ebase = g * EPG;
  const int nbase = g * n_new;
  hist[t] = 0;
  __syncthreads();
  int ls[4], ld[4];
#pragma unroll
  for (int i = 0; i < 4; ++i) {
    int e = ebase + t + i * 512;
    int s = src_in[e], d = dst_in[e];
    if (mapping) {
      s = (s >= 0) ? mapping[s] : -1;
      d = (d >= 0) ? mapping[d] : -1;
      if (s < 0 || d < 0) { s = -1; d = -1; }
    }
    src_out[e] = s; dst_out[e] = d;
    ls[i] = (s >= 0) ? (s - nbase) : -1;
    ld[i] = (d >= 0) ? (d - nbase) : -1;
    if (ld[i] >= 0) atomicAdd(&hist[ld[i]], 1);
  }
  __syncthreads();
  int v = (t < n_new) ? hist[t] : 0;
  scan[t] = v;
  __syncthreads();
  for (int dlt = 1; dlt < 512; dlt <<= 1) {
    int add = (t >= dlt) ? scan[t - dlt] : 0;
    __syncthreads();
    scan[t] += add;
    __syncthreads();
  }
  if (t < n_new) {
    int excl = scan[t] - v;
    counts[nbase + t] = v;
    offs[nbase + t] = g * EPG + excl;
    cursor[t] = excl;
  }
  __syncthreads();
#pragma unroll
  for (int i = 0; i < 4; ++i) {
    if (ld[i] >= 0) {
      int pos = atomicAdd(&cursor[ld[i]], 1);
      slots[ebase + pos] = ls[i];
    }
  }
}

// ---------------- LDS-staged aggregation with on-the-fly pooling
#define GCH  32
#define GPAD 36
__global__ __launch_bounds__(256) void gather_lds_k(
    const float* __restrict__ x, const int* __restrict__ sel,
    const float* __restrict__ gates, const int* __restrict__ slots,
    const int* __restrict__ off, const int* __restrict__ counts,
    float* __restrict__ agg, int n_per_g)
{
  __shared__ float xs[NODES_PER_G * GPAD];
  const int g = blockIdx.x, ch = blockIdx.y;
  const int tid = threadIdx.x;
  const int c0 = ch * GCH;
  const int rowbase = g * n_per_g;
  const int nv4 = n_per_g * 8;
  for (int v = tid; v < nv4; v += 256) {
    int r = v >> 3, c4 = (v & 7) * 4;
    int srow; float gt;
    if (sel) { srow = sel[rowbase + r]; gt = gates[rowbase + r]; }
    else     { srow = rowbase + r;      gt = 1.0f; }
    float4 t = *(const float4*)&x[(size_t)srow * FDIM + c0 + c4];
    t.x *= gt; t.y *= gt; t.z *= gt; t.w *= gt;
    *(float4*)&xs[r * GPAD + c4] = t;
  }
  __syncthreads();
  const int nlane = tid & 7;
  const int nslot = tid >> 3;
  for (int n = nslot; n < n_per_g; n += 32) {
    int gn = rowbase + n;
    int deg = counts[gn];
    int base = off[gn];
    float4 a = make_float4(0.f, 0.f, 0.f, 0.f);
    for (int d = 0; d < deg; ++d) {
      int s = slots[base + d];
      float4 v = *(const float4*)&xs[s * GPAD + nlane * 4];
      a.x += v.x; a.y += v.y; a.z += v.z; a.w += v.w;
    }
    *(float4*)&agg[(size_t)gn * FDIM + c0 + nlane * 4] = a;
  }
}

// ---------------- conv v3 (bf16x3 MFMA, W pre-split, A global->reg, fused score)
__global__ __launch_bounds__(256) void conv_mfma_k(
    const float* __restrict__ Asrc, const int* __restrict__ sel,
    const float* __restrict__ gates,
    const __bf16* __restrict__ W1hl,
    const float* __restrict__ A2,
    const __bf16* __restrict__ W2hl,
    const float* __restrict__ bias, const float* __restrict__ p,
    const float* __restrict__ nrm, float* __restrict__ C,
    float* __restrict__ score, int M)
{
  __shared__ __bf16 Wh[128 * 72];
  __shared__ __bf16 Wl[128 * 72];

  const int tid  = threadIdx.x;
  const int lane = tid & 63;
  const int w    = tid >> 6;
  const int row0 = blockIdx.x * 128;
  const int l15  = lane & 15;
  const int lg   = lane >> 4;

  f32x4 acc[2][8];
#pragma unroll
  for (int rf = 0; rf < 2; ++rf)
#pragma unroll
    for (int cf = 0; cf < 8; ++cf) acc[rf][cf] = (f32x4){0.f, 0.f, 0.f, 0.f};

  const int grow0 = row0 + w * 32 + l15;
  const int grow1 = grow0 + 16;

  for (int pass = 0; pass < 2; ++pass) {
    const float* __restrict__ A = pass ? A2 : Asrc;
    const __bf16* __restrict__ Whl = pass ? W2hl : W1hl;
    const bool use_sel = (pass == 0) && (sel != nullptr);
    int srow0 = use_sel ? sel[grow0] : grow0;
    int srow1 = use_sel ? sel[grow1] : grow1;
    float gt0 = use_sel ? gates[grow0] : 1.0f;
    float gt1 = use_sel ? gates[grow1] : 1.0f;

    for (int half = 0; half < 2; ++half) {
      const int k0 = half * 64;
      __syncthreads();
      for (int v = tid; v < 1024; v += 256) {
        int c = v >> 3, chn = (v & 7) * 8;
        *(bf16x8*)&Wh[c * 72 + chn] = *(const bf16x8*)&Whl[c * 128 + k0 + chn];
        *(bf16x8*)&Wl[c * 72 + chn] = *(const bf16x8*)&Whl[16384 + c * 128 + k0 + chn];
      }
      __syncthreads();

      bf16x8 ah[2][2], al[2][2];
#pragma unroll
      for (int rf = 0; rf < 2; ++rf) {
        int srow = rf ? srow1 : srow0;
        float gt = rf ? gt1 : gt0;
#pragma unroll
        for (int kc = 0; kc < 2; ++kc) {
          const float* ap = &A[(size_t)srow * FDIM + k0 + kc * 32 + lg * 8];
          float4 u0 = *(const float4*)ap;
          float4 u1 = *(const float4*)(ap + 4);
          float av[8] = {u0.x, u0.y, u0.z, u0.w, u1.x, u1.y, u1.z, u1.w};
#pragma unroll
          for (int j = 0; j < 8; ++j) {
            float vv = av[j] * gt;
            __bf16 h = (__bf16)vv;
            ah[rf][kc][j] = h;
            al[rf][kc][j] = (__bf16)(vv - (float)h);
          }
        }
      }
#pragma unroll
      for (int kc = 0; kc < 2; ++kc) {
        const int koff = kc * 32 + lg * 8;
#pragma unroll
        for (int cf = 0; cf < 8; ++cf) {
          const int bo = (cf * 16 + l15) * 72 + koff;
          bf16x8 bh = *(const bf16x8*)&Wh[bo];
          bf16x8 bl = *(const bf16x8*)&Wl[bo];
          acc[0][cf] = mfma16(ah[0][kc], bh, acc[0][cf]);
          acc[0][cf] = mfma16(ah[0][kc], bl, acc[0][cf]);
          acc[0][cf] = mfma16(al[0][kc], bh, acc[0][cf]);
          acc[1][cf] = mfma16(ah[1][kc], bh, acc[1][cf]);
          acc[1][cf] = mfma16(ah[1][kc], bl, acc[1][cf]);
          acc[1][cf] = mfma16(al[1][kc], bh, acc[1][cf]);
        }
      }
    }
  }

  const float nv = nrm[0];
  float bv[8], pv[8];
#pragma unroll
  for (int cf = 0; cf < 8; ++cf) {
    int col = cf * 16 + l15;
    bv[cf] = bias[col];
    pv[cf] = p[col];
  }
#pragma unroll
  for (int rf = 0; rf < 2; ++rf) {
#pragma unroll
    for (int j = 0; j < 4; ++j) {
      int row = row0 + w * 32 + rf * 16 + lg * 4 + j;
      float* crow = &C[(size_t)row * FDIM];
      float rsv = 0.f;
#pragma unroll
      for (int cf = 0; cf < 8; ++cf) {
        float val = acc[rf][cf][j] + bv[cf];
        val = fmaxf(val, 0.f);
        crow[cf * 16 + l15] = val;
        rsv += val * pv[cf];
      }
      rsv += __shfl_xor(rsv, 1, 16);
      rsv += __shfl_xor(rsv, 2, 16);
      rsv += __shfl_xor(rsv, 4, 16);
      rsv += __shfl_xor(rsv, 8, 16);
      if (l15 == 0) score[row] = rsv / nv;
    }
  }
}

// ---------------- per-graph top-k via bitonic sort; emits sel, mapping, gates
__global__ __launch_bounds__(512) void topk_sort_k(
    const float* __restrict__ score, int n_old, int k_new,
    int* __restrict__ sel, int* __restrict__ mapping, float* __restrict__ gates)
{
  __shared__ float sv[512];
  __shared__ int   si[512];
  int b = blockIdx.x, t = threadIdx.x;
  sv[t] = (t < n_old) ? -score[(size_t)b * n_old + t] : 3.0e38f;
  si[t] = t;
  __syncthreads();
  for (int k = 2; k <= 512; k <<= 1) {
    for (int j = k >> 1; j > 0; j >>= 1) {
      int ixj = t ^ j;
      if (ixj > t) {
        bool up = ((t & k) == 0);
        float a = sv[t], c = sv[ixj];
        if ((a > c) == up) {
          sv[t] = c; sv[ixj] = a;
          int tmp = si[t]; si[t] = si[ixj]; si[ixj] = tmp;
        }
      }
      __syncthreads();
    }
  }
  if (t < n_old) {
    int old_g = b * n_old + si[t];
    if (t < k_new) {
      sel[b * k_new + t] = old_g;
      mapping[old_g] = b * k_new + t;
      gates[b * k_new + t] = tanhf(-sv[t]);
    } else {
      mapping[old_g] = -1;
    }
  }
}

// ---------------- readout over pooled rows (no materialization)
__global__ __launch_bounds__(256) void readout_k(
    const float* __restrict__ x, const int* __restrict__ sel,
    const float* __restrict__ gates, float* __restrict__ g, int k)
{
  __shared__ float lmx[32 * 36];
  __shared__ float lsm[32 * 36];
  const int b = blockIdx.x, ch = blockIdx.y;
  const int c0 = ch * 32;
  const int tid = threadIdx.x;
  const int lane = tid & 7;
  const int slot = tid >> 3;
  float4 mx = make_float4(-3.0e38f, -3.0e38f, -3.0e38f, -3.0e38f);
  float4 sm = make_float4(0.f, 0.f, 0.f, 0.f);
  for (int n = slot; n < k; n += 32) {
    int node = b * k + n;
    int old = sel[node];
    float gate = gates[node];
    float4 v = *(const float4*)&x[(size_t)old * FDIM + c0 + lane * 4];
    v.x *= gate; v.y *= gate; v.z *= gate; v.w *= gate;
    mx.x = fmaxf(mx.x, v.x); mx.y = fmaxf(mx.y, v.y);
    mx.z = fmaxf(mx.z, v.z); mx.w = fmaxf(mx.w, v.w);
    sm.x += v.x; sm.y += v.y; sm.z += v.z; sm.w += v.w;
  }
  float* pm = &lmx[slot * 36 + lane * 4];
  float* ps = &lsm[slot * 36 + lane * 4];
  pm[0] = mx.x; pm[1] = mx.y; pm[2] = mx.z; pm[3] = mx.w;
  ps[0] = sm.x; ps[1] = sm.y; ps[2] = sm.z; ps[3] = sm.w;
  __syncthreads();
  for (int s = 16; s > 0; s >>= 1) {
    if (slot < s) {
#pragma unroll
      for (int j = 0; j < 4; ++j) {
        int a = slot * 36 + lane * 4 + j;
        int bb = (slot + s) * 36 + lane * 4 + j;
        lmx[a] = fmaxf(lmx[a], lmx[bb]);
        lsm[a] += lsm[bb];
      }
    }
    __syncthreads();
  }
  if (slot == 0) {
    float inv_k = 1.f / (float)k;
#pragma unroll
    for (int j = 0; j < 4; ++j) {
      int c = c0 + lane * 4 + j;
      g[b * 256 + c]       += lmx[lane * 4 + j];
      g[b * 256 + 128 + c] += lsm[lane * 4 + j] * inv_k;
    }
  }
}

// ---------------- head1: h1 = relu(bn1(g @ fc1_W + b1)); 16 blocks x 8 cols
// thread t = row t (256 rows == 256 threads). K=256 fully unrolled.
__global__ __launch_bounds__(256) void head1_k(
    const float* __restrict__ g, const float* __restrict__ W,
    const float* __restrict__ bias, const float* __restrict__ gamma,
    const float* __restrict__ beta, float* __restrict__ h1)
{
  __shared__ float wsl[256 * 8];         // W[:, c0..c0+7]
  __shared__ float rsum[256 * 9];
  __shared__ float rsq[256 * 9];
  const int c0 = blockIdx.x * 8;
  const int t = threadIdx.x;
#pragma unroll
  for (int j = 0; j < 8; ++j) wsl[t * 8 + j] = W[t * 128 + c0 + j];
  __syncthreads();
  float acc[8] = {0.f, 0.f, 0.f, 0.f, 0.f, 0.f, 0.f, 0.f};
  const float* grow = &g[t * 256];
#pragma unroll
  for (int k = 0; k < 256; k += 4) {
    float4 gv = *(const float4*)&grow[k];
#pragma unroll
    for (int j = 0; j < 8; ++j) {
      acc[j] += gv.x * wsl[(k + 0) * 8 + j] + gv.y * wsl[(k + 1) * 8 + j]
              + gv.z * wsl[(k + 2) * 8 + j] + gv.w * wsl[(k + 3) * 8 + j];
    }
  }
#pragma unroll
  for (int j = 0; j < 8; ++j) {
    acc[j] += bias[c0 + j];
    rsum[t * 9 + j] = acc[j];
    rsq[t * 9 + j] = acc[j] * acc[j];
  }
  __syncthreads();
  for (int s = 128; s > 0; s >>= 1) {
    if (t < s) {
#pragma unroll
      for (int j = 0; j < 8; ++j) {
        rsum[t * 9 + j] += rsum[(t + s) * 9 + j];
        rsq[t * 9 + j]  += rsq[(t + s) * 9 + j];
      }
    }
    __syncthreads();
  }
#pragma unroll
  for (int j = 0; j < 8; ++j) {
    float m = rsum[j] * (1.f / 256.f);
    float var = rsq[j] * (1.f / 256.f) - m * m;
    float o = gamma[c0 + j] * (acc[j] - m) * rsqrtf(var + 1e-5f) + beta[c0 + j];
    h1[t * 128 + c0 + j] = fmaxf(o, 0.f);
  }
}

// ---------------- head2: h2 = relu(bn2(h1 @ fc2_W + b2)); 8 blocks x 8 cols
__global__ __launch_bounds__(256) void head2_k(
    const float* __restrict__ h1, const float* __restrict__ W,
    const float* __restrict__ bias, const float* __restrict__ gamma,
    const float* __restrict__ beta, float* __restrict__ h2)
{
  __shared__ float wsl[128 * 8];         // W[:, c0..c0+7]
  __shared__ float rsum[256 * 9];
  __shared__ float rsq[256 * 9];
  const int c0 = blockIdx.x * 8;
  const int t = threadIdx.x;
  if (t < 128) {
#pragma unroll
    for (int j = 0; j < 8; ++j) wsl[t * 8 + j] = W[t * 64 + c0 + j];
  }
  __syncthreads();
  float acc[8] = {0.f, 0.f, 0.f, 0.f, 0.f, 0.f, 0.f, 0.f};
  const float* hrow = &h1[t * 128];
#pragma unroll
  for (int k = 0; k < 128; k += 4) {
    float4 gv = *(const float4*)&hrow[k];
#pragma unroll
    for (int j = 0; j < 8; ++j) {
      acc[j] += gv.x * wsl[(k + 0) * 8 + j] + gv.y * wsl[(k + 1) * 8 + j]
              + gv.z * wsl[(k + 2) * 8 + j] + gv.w * wsl[(k + 3) * 8 + j];
    }
  }
#pragma unroll
  for (int j = 0; j < 8; ++j) {
    acc[j] += bias[c0 + j];
    rsum[t * 9 + j] = acc[j];
    rsq[t * 9 + j] = acc[j] * acc[j];
  }
  __syncthreads();
  for (int s = 128; s > 0; s >>= 1) {
    if (t < s) {
#pragma unroll
      for (int j = 0; j < 8; ++j) {
        rsum[t * 9 + j] += rsum[(t + s) * 9 + j];
        rsq[t * 9 + j]  += rsq[(t + s) * 9 + j];
      }
    }
    __syncthreads();
  }
#pragma unroll
  for (int j = 0; j < 8; ++j) {
    float m = rsum[j] * (1.f / 256.f);
    float var = rsq[j] * (1.f / 256.f) - m * m;
    float o = gamma[c0 + j] * (acc[j] - m) * rsqrtf(var + 1e-5f) + beta[c0 + j];
    h2[t * 64 + c0 + j] = fmaxf(o, 0.f);   // extra relu is idempotent
  }
}

// ---------------- out[nid] = sigmoid(dot(emb_item[item_id[nid]], g2[graph]))
__global__ __launch_bounds__(256) void final_k(
    const int* __restrict__ item_id, const float* __restrict__ emb_item,
    const float* __restrict__ g2, float* __restrict__ out, int total)
{
  int nid = blockIdx.x * 256 + threadIdx.x;
  if (nid >= total) return;
  int b = nid >> 9;
  const float* e = &emb_item[(size_t)item_id[nid] * EMBD];
  const float* gg = &g2[(size_t)b * 64];
  float s = 0.f;
#pragma unroll
  for (int j = 0; j < 64; j += 4) {
    float4 a = *(const float4*)&e[j];
    float4 c = *(const float4*)&gg[j];
    s += a.x * c.x + a.y * c.y + a.z * c.z + a.w * c.w;
  }
  out[nid] = 1.f / (1.f + expf(-s));
}

// ---------------------------------------------------------------------------
extern "C" void kernel_launch(void* const* d_in, const int* in_sizes, int n_in,
                              void* d_out, int out_size, void* d_ws, size_t ws_size,
                              hipStream_t stream)
{
  const int*   item_id  = (const int*)  d_in[0];
  const int*   cat_id   = (const int*)  d_in[1];
  const int*   src_in   = (const int*)  d_in[2];
  const int*   dst_in   = (const int*)  d_in[3];
  const float* emb_item = (const float*)d_in[4];
  const float* emb_cat  = (const float*)d_in[5];
  const float* W1r = (const float*)d_in[6];
  const float* W1n = (const float*)d_in[7];
  const float* b1  = (const float*)d_in[8];
  const float* p1  = (const float*)d_in[9];
  const float* W2r = (const float*)d_in[10];
  const float* W2n = (const float*)d_in[11];
  const float* b2  = (const float*)d_in[12];
  const float* p2  = (const float*)d_in[13];
  const float* W3r = (const float*)d_in[14];
  const float* W3n = (const float*)d_in[15];
  const float* b3  = (const float*)d_in[16];
  const float* p3  = (const float*)d_in[17];
  const float* fc1_W = (const float*)d_in[18];
  const float* fc1_b = (const float*)d_in[19];
  const float* bn1_g = (const float*)d_in[20];
  const float* bn1_b = (const float*)d_in[21];
  const float* fc2_W = (const float*)d_in[22];
  const float* fc2_b = (const float*)d_in[23];
  const float* bn2_g = (const float*)d_in[24];
  const float* bn2_b = (const float*)d_in[25];
  float* out = (float*)d_out;

  const int TN = TOTAL_NODES;
  const int E  = E_TOTAL;
  const int k1 = 461, k2 = 415, k3 = 374;
  const int M1 = TN;              // 131072
  const int M2 = NUM_GRAPHS * k1; // 118016
  const int M3 = NUM_GRAPHS * k2; // 106240

  char* ws = (char*)d_ws;
  size_t off = 0;
  auto carve = [&](size_t bytes) { char* p = ws + off; off += align256(bytes); return p; };
  float*  buf0   = (float*) carve((size_t)TN * FDIM * 4);
  float*  buf1   = (float*) carve((size_t)TN * FDIM * 4);
  float*  score  = (float*) carve((size_t)TN * 4);
  int*    sel    = (int*)   carve((size_t)TN * 4);
  int*    mapping= (int*)   carve((size_t)TN * 4);
  float*  gates  = (float*) carve((size_t)TN * 4);
  int*    srcw   = (int*)   carve((size_t)E * 4);
  int*    dstw   = (int*)   carve((size_t)E * 4);
  int*    counts = (int*)   carve((size_t)TN * 4);
  int*    offs   = (int*)   carve((size_t)TN * 4);
  int*    slots  = (int*)   carve((size_t)E * 4);
  __bf16* wbuf   = (__bf16*)carve(6 * 2 * 16384 * 2);
  float*  g      = (float*) carve(256 * 256 * 4);
  float*  h1     = (float*) carve(256 * 128 * 4);
  float*  h2     = (float*) carve(256 * 64 * 4);
  float*  nrm    = (float*) carve(256);
  if (off > ws_size) return;

  dim3 b256(256);
  auto blocks = [](long long work, int bs) { return dim3((unsigned)((work + bs - 1) / bs)); };

  const __bf16* W1r_hl = wbuf + 0 * 2 * 16384;
  const __bf16* W1n_hl = wbuf + 1 * 2 * 16384;
  const __bf16* W2r_hl = wbuf + 2 * 2 * 16384;
  const __bf16* W2n_hl = wbuf + 3 * 2 * 16384;
  const __bf16* W3r_hl = wbuf + 4 * 2 * 16384;
  const __bf16* W3n_hl = wbuf + 5 * 2 * 16384;

  hipMemsetAsync(g, 0, 256 * 256 * 4, stream);
  wprep_k<<<dim3(64, 6), b256, 0, stream>>>(W1r, W1n, W2r, W2n, W3r, W3n, wbuf);
  pnorm3_k<<<dim3(1), dim3(128), 0, stream>>>(p1, p2, p3, nrm);
  gather_embed_k<<<blocks((long long)TN * 32, 256), b256, 0, stream>>>(
      item_id, cat_id, emb_item, emb_cat, buf0, TN);

  // ================= stage 1 (x0 = buf0, dense) =================
  csr_build_k<<<dim3(NUM_GRAPHS), dim3(512), 0, stream>>>(
      src_in, dst_in, nullptr, srcw, dstw, slots, counts, offs, NODES_PER_G);
  gather_lds_k<<<dim3(NUM_GRAPHS, 4), b256, 0, stream>>>(
      buf0, nullptr, nullptr, slots, offs, counts, buf1, NODES_PER_G);
  conv_mfma_k<<<dim3(M1 / 128), b256, 0, stream>>>(
      buf0, nullptr, nullptr, W1r_hl, buf1, W1n_hl, b1, p1, nrm + 0, buf0, score, M1);
  topk_sort_k<<<dim3(NUM_GRAPHS), dim3(512), 0, stream>>>(
      score, NODES_PER_G, k1, sel, mapping, gates);
  readout_k<<<dim3(NUM_GRAPHS, 4), b256, 0, stream>>>(buf0, sel, gates, g, k1);

  // ================= stage 2 (x1 = buf0 via sel/gates) =================
  csr_build_k<<<dim3(NUM_GRAPHS), dim3(512), 0, stream>>>(
      srcw, dstw, mapping, srcw, dstw, slots, counts, offs, k1);
  gather_lds_k<<<dim3(NUM_GRAPHS, 4), b256, 0, stream>>>(
      buf0, sel, gates, slots, offs, counts, buf1, k1);
  conv_mfma_k<<<dim3(M2 / 128), b256, 0, stream>>>(
      buf0, sel, gates, W2r_hl, buf1, W2n_hl, b2, p2, nrm + 1, buf1, score, M2);
  topk_sort_k<<<dim3(NUM_GRAPHS), dim3(512), 0, stream>>>(
      score, k1, k2, sel, mapping, gates);
  readout_k<<<dim3(NUM_GRAPHS, 4), b256, 0, stream>>>(buf1, sel, gates, g, k2);

  // ================= stage 3 (x2 = buf1 via sel/gates) =================
  csr_build_k<<<dim3(NUM_GRAPHS), dim3(512), 0, stream>>>(
      srcw, dstw, mapping, srcw, dstw, slots, counts, offs, k2);
  gather_lds_k<<<dim3(NUM_GRAPHS, 4), b256, 0, stream>>>(
      buf1, sel, gates, slots, offs, counts, buf0, k2);
  conv_mfma_k<<<dim3(M3 / 128), b256, 0, stream>>>(
      buf1, sel, gates, W3r_hl, buf0, W3n_hl, b3, p3, nrm + 2, buf0, score, M3);
  topk_sort_k<<<dim3(NUM_GRAPHS), dim3(512), 0, stream>>>(
      score, k2, k3, sel, mapping, gates);
  readout_k<<<dim3(NUM_GRAPHS, 4), b256, 0, stream>>>(buf0, sel, gates, g, k3);

  // ================= head (fused fc+bn+relu) =================
  head1_k<<<dim3(16), b256, 0, stream>>>(g, fc1_W, fc1_b, bn1_g, bn1_b, h1);
  head2_k<<<dim3(8), b256, 0, stream>>>(h1, fc2_W, fc2_b, bn2_g, bn2_b, h2);

  final_k<<<blocks(TN, 256), b256, 0, stream>>>(item_id, emb_item, h2, out, TN);
}

// Round 7
// 409.015 us; speedup vs baseline: 7.5962x; 1.1578x over previous
//
#include <hip/hip_runtime.h>
#include <hip/hip_bf16.h>
#include <math.h>

// ---------------------------------------------------------------------------
// NetNode: 3x (GraphConv -> TopKPooling -> readout) + FC/BN head + per-node dot
// B=256, N=512, E=2048/graph, F=128, EMB=64. k1=461, k2=415, k3=374.
// R7: LDS-staged gather (74us, 19% occ, latency-bound) -> direct register
//     gather, no LDS, with csr_build pre-resolving sel/gate into packed
//     int2 slots (one 8B + one 16B load per edge).
// ---------------------------------------------------------------------------

#define TOTAL_NODES 131072   // B*N
#define NUM_GRAPHS  256
#define NODES_PER_G 512
#define E_TOTAL     524288   // B*E
#define EPG         2048     // edges per graph (slot capacity)
#define FDIM        128
#define EMBD        64

typedef __bf16 bf16x8 __attribute__((ext_vector_type(8)));
typedef float  f32x4  __attribute__((ext_vector_type(4)));

static __device__ __forceinline__ f32x4 mfma16(bf16x8 a, bf16x8 b, f32x4 c) {
  return __builtin_amdgcn_mfma_f32_16x16x32_bf16(a, b, c, 0, 0, 0);
}

static inline size_t align256(size_t x) { return (x + 255) & ~size_t(255); }

// ---------------- gather embeddings
__global__ __launch_bounds__(256) void gather_embed_k(
    const int* __restrict__ item_id, const int* __restrict__ cat_id,
    const float* __restrict__ emb_item, const float* __restrict__ emb_cat,
    float* __restrict__ x, int total)
{
  int i = blockIdx.x * 256 + threadIdx.x;
  int node = i >> 5, part = i & 31;
  if (node >= total) return;
  float4 v;
  if (part < 16) {
    v = *(const float4*)&emb_item[(size_t)item_id[node] * EMBD + part * 4];
  } else {
    v = *(const float4*)&emb_cat[(size_t)cat_id[node] * EMBD + (part - 16) * 4];
  }
  *(float4*)&x[(size_t)node * FDIM + part * 4] = v;
}

// ---------------- W pre-split: W[k][n] fp32 -> Wh/Wl[n][k] bf16 (hi/lo)
__global__ __launch_bounds__(256) void wprep_k(
    const float* __restrict__ w0, const float* __restrict__ w1,
    const float* __restrict__ w2, const float* __restrict__ w3,
    const float* __restrict__ w4, const float* __restrict__ w5,
    __bf16* __restrict__ wout)
{
  const float* ws[6] = {w0, w1, w2, w3, w4, w5};
  int mat = blockIdx.y;
  int idx = blockIdx.x * 256 + threadIdx.x;   // 0..16383
  int n = idx >> 7, k = idx & 127;
  float v = ws[mat][k * FDIM + n];
  __bf16 h = (__bf16)v;
  __bf16 l = (__bf16)(v - (float)h);
  __bf16* base = wout + (size_t)mat * 2 * 16384;
  base[idx] = h;
  base[16384 + idx] = l;
}

// ---------------- norms of p1,p2,p3 in one launch
__global__ __launch_bounds__(128) void pnorm3_k(
    const float* __restrict__ p1, const float* __restrict__ p2,
    const float* __restrict__ p3, float* __restrict__ nrm)
{
  __shared__ float ss[128];
  const float* ps[3] = {p1, p2, p3};
  int t = threadIdx.x;
  for (int m = 0; m < 3; ++m) {
    float v = ps[m][t];
    ss[t] = v * v;
    __syncthreads();
    for (int s = 64; s > 0; s >>= 1) {
      if (t < s) ss[t] += ss[t + s];
      __syncthreads();
    }
    if (t == 0) nrm[m] = sqrtf(ss[0]);
    __syncthreads();
  }
}

// ---------------- fused CSR build (+remap +sel/gate resolution)
// slot_pack[pos] = {old_row (row index into x buffer), gate bits}
__global__ __launch_bounds__(512) void csr_build_k(
    const int* __restrict__ src_in, const int* __restrict__ dst_in,
    const int* __restrict__ mapping,     // null for stage 1
    const int* __restrict__ sel_,        // null for stage 1
    const float* __restrict__ gates_,    // null for stage 1
    int* __restrict__ src_out, int* __restrict__ dst_out,
    int2* __restrict__ slot_pack, int* __restrict__ counts,
    int* __restrict__ offs, int n_new)
{
  __shared__ int hist[512];
  __shared__ int scan[512];
  __shared__ int cursor[512];
  const int g = blockIdx.x, t = threadIdx.x;
  const int ebase = g * EPG;
  const int nbase = g * n_new;
  hist[t] = 0;
  __syncthreads();
  int ls[4], ld[4];
#pragma unroll
  for (int i = 0; i < 4; ++i) {
    int e = ebase + t + i * 512;
    int s = src_in[e], d = dst_in[e];
    if (mapping) {
      s = (s >= 0) ? mapping[s] : -1;
      d = (d >= 0) ? mapping[d] : -1;
      if (s < 0 || d < 0) { s = -1; d = -1; }
    }
    src_out[e] = s; dst_out[e] = d;
    ls[i] = (s >= 0) ? (s - nbase) : -1;
    ld[i] = (d >= 0) ? (d - nbase) : -1;
    if (ld[i] >= 0) atomicAdd(&hist[ld[i]], 1);
  }
  __syncthreads();
  int v = (t < n_new) ? hist[t] : 0;
  scan[t] = v;
  __syncthreads();
  for (int dlt = 1; dlt < 512; dlt <<= 1) {
    int add = (t >= dlt) ? scan[t - dlt] : 0;
    __syncthreads();
    scan[t] += add;
    __syncthreads();
  }
  if (t < n_new) {
    int excl = scan[t] - v;
    counts[nbase + t] = v;
    offs[nbase + t] = g * EPG + excl;
    cursor[t] = excl;
  }
  __syncthreads();
#pragma unroll
  for (int i = 0; i < 4; ++i) {
    if (ld[i] >= 0) {
      int pos = atomicAdd(&cursor[ld[i]], 1);
      int sg = nbase + ls[i];
      int oldr = sel_ ? sel_[sg] : sg;
      float gt = gates_ ? gates_[sg] : 1.0f;
      slot_pack[ebase + pos] = make_int2(oldr, __float_as_int(gt));
    }
  }
}

// ---------------- direct register gather: agg[i] = sum gate_e * x[old_e]
// 32 lanes per node (full 128-f row), no LDS, high occupancy.
__global__ __launch_bounds__(256) void gather_direct_k(
    const float* __restrict__ x, const int2* __restrict__ slot_pack,
    const int* __restrict__ off, const int* __restrict__ counts,
    float* __restrict__ agg, int M)
{
  int i = blockIdx.x * 256 + threadIdx.x;
  int node = i >> 5, lane = i & 31;
  if (node >= M) return;
  int deg = counts[node];
  int base = off[node];
  float4 a = make_float4(0.f, 0.f, 0.f, 0.f);
  for (int d = 0; d < deg; ++d) {
    int2 sp = slot_pack[base + d];
    float gt = __int_as_float(sp.y);
    float4 v = *(const float4*)&x[(size_t)sp.x * FDIM + lane * 4];
    a.x += gt * v.x; a.y += gt * v.y; a.z += gt * v.z; a.w += gt * v.w;
  }
  *(float4*)&agg[(size_t)node * FDIM + lane * 4] = a;
}

// ---------------- conv v3 (bf16x3 MFMA, W pre-split, A global->reg, fused score)
__global__ __launch_bounds__(256) void conv_mfma_k(
    const float* __restrict__ Asrc, const int* __restrict__ sel,
    const float* __restrict__ gates,
    const __bf16* __restrict__ W1hl,
    const float* __restrict__ A2,
    const __bf16* __restrict__ W2hl,
    const float* __restrict__ bias, const float* __restrict__ p,
    const float* __restrict__ nrm, float* __restrict__ C,
    float* __restrict__ score, int M)
{
  __shared__ __bf16 Wh[128 * 72];
  __shared__ __bf16 Wl[128 * 72];

  const int tid  = threadIdx.x;
  const int lane = tid & 63;
  const int w    = tid >> 6;
  const int row0 = blockIdx.x * 128;
  const int l15  = lane & 15;
  const int lg   = lane >> 4;

  f32x4 acc[2][8];
#pragma unroll
  for (int rf = 0; rf < 2; ++rf)
#pragma unroll
    for (int cf = 0; cf < 8; ++cf) acc[rf][cf] = (f32x4){0.f, 0.f, 0.f, 0.f};

  const int grow0 = row0 + w * 32 + l15;
  const int grow1 = grow0 + 16;

  for (int pass = 0; pass < 2; ++pass) {
    const float* __restrict__ A = pass ? A2 : Asrc;
    const __bf16* __restrict__ Whl = pass ? W2hl : W1hl;
    const bool use_sel = (pass == 0) && (sel != nullptr);
    int srow0 = use_sel ? sel[grow0] : grow0;
    int srow1 = use_sel ? sel[grow1] : grow1;
    float gt0 = use_sel ? gates[grow0] : 1.0f;
    float gt1 = use_sel ? gates[grow1] : 1.0f;

    for (int half = 0; half < 2; ++half) {
      const int k0 = half * 64;
      __syncthreads();
      for (int v = tid; v < 1024; v += 256) {
        int c = v >> 3, chn = (v & 7) * 8;
        *(bf16x8*)&Wh[c * 72 + chn] = *(const bf16x8*)&Whl[c * 128 + k0 + chn];
        *(bf16x8*)&Wl[c * 72 + chn] = *(const bf16x8*)&Whl[16384 + c * 128 + k0 + chn];
      }
      __syncthreads();

      bf16x8 ah[2][2], al[2][2];
#pragma unroll
      for (int rf = 0; rf < 2; ++rf) {
        int srow = rf ? srow1 : srow0;
        float gt = rf ? gt1 : gt0;
#pragma unroll
        for (int kc = 0; kc < 2; ++kc) {
          const float* ap = &A[(size_t)srow * FDIM + k0 + kc * 32 + lg * 8];
          float4 u0 = *(const float4*)ap;
          float4 u1 = *(const float4*)(ap + 4);
          float av[8] = {u0.x, u0.y, u0.z, u0.w, u1.x, u1.y, u1.z, u1.w};
#pragma unroll
          for (int j = 0; j < 8; ++j) {
            float vv = av[j] * gt;
            __bf16 h = (__bf16)vv;
            ah[rf][kc][j] = h;
            al[rf][kc][j] = (__bf16)(vv - (float)h);
          }
        }
      }
#pragma unroll
      for (int kc = 0; kc < 2; ++kc) {
        const int koff = kc * 32 + lg * 8;
#pragma unroll
        for (int cf = 0; cf < 8; ++cf) {
          const int bo = (cf * 16 + l15) * 72 + koff;
          bf16x8 bh = *(const bf16x8*)&Wh[bo];
          bf16x8 bl = *(const bf16x8*)&Wl[bo];
          acc[0][cf] = mfma16(ah[0][kc], bh, acc[0][cf]);
          acc[0][cf] = mfma16(ah[0][kc], bl, acc[0][cf]);
          acc[0][cf] = mfma16(al[0][kc], bh, acc[0][cf]);
          acc[1][cf] = mfma16(ah[1][kc], bh, acc[1][cf]);
          acc[1][cf] = mfma16(ah[1][kc], bl, acc[1][cf]);
          acc[1][cf] = mfma16(al[1][kc], bh, acc[1][cf]);
        }
      }
    }
  }

  const float nv = nrm[0];
  float bv[8], pv[8];
#pragma unroll
  for (int cf = 0; cf < 8; ++cf) {
    int col = cf * 16 + l15;
    bv[cf] = bias[col];
    pv[cf] = p[col];
  }
#pragma unroll
  for (int rf = 0; rf < 2; ++rf) {
#pragma unroll
    for (int j = 0; j < 4; ++j) {
      int row = row0 + w * 32 + rf * 16 + lg * 4 + j;
      float* crow = &C[(size_t)row * FDIM];
      float rsv = 0.f;
#pragma unroll
      for (int cf = 0; cf < 8; ++cf) {
        float val = acc[rf][cf][j] + bv[cf];
        val = fmaxf(val, 0.f);
        crow[cf * 16 + l15] = val;
        rsv += val * pv[cf];
      }
      rsv += __shfl_xor(rsv, 1, 16);
      rsv += __shfl_xor(rsv, 2, 16);
      rsv += __shfl_xor(rsv, 4, 16);
      rsv += __shfl_xor(rsv, 8, 16);
      if (l15 == 0) score[row] = rsv / nv;
    }
  }
}

// ---------------- per-graph top-k via bitonic sort; emits sel, mapping, gates
__global__ __launch_bounds__(512) void topk_sort_k(
    const float* __restrict__ score, int n_old, int k_new,
    int* __restrict__ sel, int* __restrict__ mapping, float* __restrict__ gates)
{
  __shared__ float sv[512];
  __shared__ int   si[512];
  int b = blockIdx.x, t = threadIdx.x;
  sv[t] = (t < n_old) ? -score[(size_t)b * n_old + t] : 3.0e38f;
  si[t] = t;
  __syncthreads();
  for (int k = 2; k <= 512; k <<= 1) {
    for (int j = k >> 1; j > 0; j >>= 1) {
      int ixj = t ^ j;
      if (ixj > t) {
        bool up = ((t & k) == 0);
        float a = sv[t], c = sv[ixj];
        if ((a > c) == up) {
          sv[t] = c; sv[ixj] = a;
          int tmp = si[t]; si[t] = si[ixj]; si[ixj] = tmp;
        }
      }
      __syncthreads();
    }
  }
  if (t < n_old) {
    int old_g = b * n_old + si[t];
    if (t < k_new) {
      sel[b * k_new + t] = old_g;
      mapping[old_g] = b * k_new + t;
      gates[b * k_new + t] = tanhf(-sv[t]);
    } else {
      mapping[old_g] = -1;
    }
  }
}

// ---------------- readout over pooled rows (no materialization)
__global__ __launch_bounds__(256) void readout_k(
    const float* __restrict__ x, const int* __restrict__ sel,
    const float* __restrict__ gates, float* __restrict__ g, int k)
{
  __shared__ float lmx[32 * 36];
  __shared__ float lsm[32 * 36];
  const int b = blockIdx.x, ch = blockIdx.y;
  const int c0 = ch * 32;
  const int tid = threadIdx.x;
  const int lane = tid & 7;
  const int slot = tid >> 3;
  float4 mx = make_float4(-3.0e38f, -3.0e38f, -3.0e38f, -3.0e38f);
  float4 sm = make_float4(0.f, 0.f, 0.f, 0.f);
  for (int n = slot; n < k; n += 32) {
    int node = b * k + n;
    int old = sel[node];
    float gate = gates[node];
    float4 v = *(const float4*)&x[(size_t)old * FDIM + c0 + lane * 4];
    v.x *= gate; v.y *= gate; v.z *= gate; v.w *= gate;
    mx.x = fmaxf(mx.x, v.x); mx.y = fmaxf(mx.y, v.y);
    mx.z = fmaxf(mx.z, v.z); mx.w = fmaxf(mx.w, v.w);
    sm.x += v.x; sm.y += v.y; sm.z += v.z; sm.w += v.w;
  }
  float* pm = &lmx[slot * 36 + lane * 4];
  float* ps = &lsm[slot * 36 + lane * 4];
  pm[0] = mx.x; pm[1] = mx.y; pm[2] = mx.z; pm[3] = mx.w;
  ps[0] = sm.x; ps[1] = sm.y; ps[2] = sm.z; ps[3] = sm.w;
  __syncthreads();
  for (int s = 16; s > 0; s >>= 1) {
    if (slot < s) {
#pragma unroll
      for (int j = 0; j < 4; ++j) {
        int a = slot * 36 + lane * 4 + j;
        int bb = (slot + s) * 36 + lane * 4 + j;
        lmx[a] = fmaxf(lmx[a], lmx[bb]);
        lsm[a] += lsm[bb];
      }
    }
    __syncthreads();
  }
  if (slot == 0) {
    float inv_k = 1.f / (float)k;
#pragma unroll
    for (int j = 0; j < 4; ++j) {
      int c = c0 + lane * 4 + j;
      g[b * 256 + c]       += lmx[lane * 4 + j];
      g[b * 256 + 128 + c] += lsm[lane * 4 + j] * inv_k;
    }
  }
}

// ---------------- head1: h1 = relu(bn1(g @ fc1_W + b1)); 16 blocks x 8 cols
__global__ __launch_bounds__(256) void head1_k(
    const float* __restrict__ g, const float* __restrict__ W,
    const float* __restrict__ bias, const float* __restrict__ gamma,
    const float* __restrict__ beta, float* __restrict__ h1)
{
  __shared__ float wsl[256 * 8];
  __shared__ float rsum[256 * 9];
  __shared__ float rsq[256 * 9];
  const int c0 = blockIdx.x * 8;
  const int t = threadIdx.x;
#pragma unroll
  for (int j = 0; j < 8; ++j) wsl[t * 8 + j] = W[t * 128 + c0 + j];
  __syncthreads();
  float acc[8] = {0.f, 0.f, 0.f, 0.f, 0.f, 0.f, 0.f, 0.f};
  const float* grow = &g[t * 256];
#pragma unroll
  for (int k = 0; k < 256; k += 4) {
    float4 gv = *(const float4*)&grow[k];
#pragma unroll
    for (int j = 0; j < 8; ++j) {
      acc[j] += gv.x * wsl[(k + 0) * 8 + j] + gv.y * wsl[(k + 1) * 8 + j]
              + gv.z * wsl[(k + 2) * 8 + j] + gv.w * wsl[(k + 3) * 8 + j];
    }
  }
#pragma unroll
  for (int j = 0; j < 8; ++j) {
    acc[j] += bias[c0 + j];
    rsum[t * 9 + j] = acc[j];
    rsq[t * 9 + j] = acc[j] * acc[j];
  }
  __syncthreads();
  for (int s = 128; s > 0; s >>= 1) {
    if (t < s) {
#pragma unroll
      for (int j = 0; j < 8; ++j) {
        rsum[t * 9 + j] += rsum[(t + s) * 9 + j];
        rsq[t * 9 + j]  += rsq[(t + s) * 9 + j];
      }
    }
    __syncthreads();
  }
#pragma unroll
  for (int j = 0; j < 8; ++j) {
    float m = rsum[j] * (1.f / 256.f);
    float var = rsq[j] * (1.f / 256.f) - m * m;
    float o = gamma[c0 + j] * (acc[j] - m) * rsqrtf(var + 1e-5f) + beta[c0 + j];
    h1[t * 128 + c0 + j] = fmaxf(o, 0.f);
  }
}

// ---------------- head2: h2 = relu(bn2(h1 @ fc2_W + b2)); 8 blocks x 8 cols
__global__ __launch_bounds__(256) void head2_k(
    const float* __restrict__ h1, const float* __restrict__ W,
    const float* __restrict__ bias, const float* __restrict__ gamma,
    const float* __restrict__ beta, float* __restrict__ h2)
{
  __shared__ float wsl[128 * 8];
  __shared__ float rsum[256 * 9];
  __shared__ float rsq[256 * 9];
  const int c0 = blockIdx.x * 8;
  const int t = threadIdx.x;
  if (t < 128) {
#pragma unroll
    for (int j = 0; j < 8; ++j) wsl[t * 8 + j] = W[t * 64 + c0 + j];
  }
  __syncthreads();
  float acc[8] = {0.f, 0.f, 0.f, 0.f, 0.f, 0.f, 0.f, 0.f};
  const float* hrow = &h1[t * 128];
#pragma unroll
  for (int k = 0; k < 128; k += 4) {
    float4 gv = *(const float4*)&hrow[k];
#pragma unroll
    for (int j = 0; j < 8; ++j) {
      acc[j] += gv.x * wsl[(k + 0) * 8 + j] + gv.y * wsl[(k + 1) * 8 + j]
              + gv.z * wsl[(k + 2) * 8 + j] + gv.w * wsl[(k + 3) * 8 + j];
    }
  }
#pragma unroll
  for (int j = 0; j < 8; ++j) {
    acc[j] += bias[c0 + j];
    rsum[t * 9 + j] = acc[j];
    rsq[t * 9 + j] = acc[j] * acc[j];
  }
  __syncthreads();
  for (int s = 128; s > 0; s >>= 1) {
    if (t < s) {
#pragma unroll
      for (int j = 0; j < 8; ++j) {
        rsum[t * 9 + j] += rsum[(t + s) * 9 + j];
        rsq[t * 9 + j]  += rsq[(t + s) * 9 + j];
      }
    }
    __syncthreads();
  }
#pragma unroll
  for (int j = 0; j < 8; ++j) {
    float m = rsum[j] * (1.f / 256.f);
    float var = rsq[j] * (1.f / 256.f) - m * m;
    float o = gamma[c0 + j] * (acc[j] - m) * rsqrtf(var + 1e-5f) + beta[c0 + j];
    h2[t * 64 + c0 + j] = fmaxf(o, 0.f);
  }
}

// ---------------- out[nid] = sigmoid(dot(emb_item[item_id[nid]], g2[graph]))
__global__ __launch_bounds__(256) void final_k(
    const int* __restrict__ item_id, const float* __restrict__ emb_item,
    const float* __restrict__ g2, float* __restrict__ out, int total)
{
  int nid = blockIdx.x * 256 + threadIdx.x;
  if (nid >= total) return;
  int b = nid >> 9;
  const float* e = &emb_item[(size_t)item_id[nid] * EMBD];
  const float* gg = &g2[(size_t)b * 64];
  float s = 0.f;
#pragma unroll
  for (int j = 0; j < 64; j += 4) {
    float4 a = *(const float4*)&e[j];
    float4 c = *(const float4*)&gg[j];
    s += a.x * c.x + a.y * c.y + a.z * c.z + a.w * c.w;
  }
  out[nid] = 1.f / (1.f + expf(-s));
}

// ---------------------------------------------------------------------------
extern "C" void kernel_launch(void* const* d_in, const int* in_sizes, int n_in,
                              void* d_out, int out_size, void* d_ws, size_t ws_size,
                              hipStream_t stream)
{
  const int*   item_id  = (const int*)  d_in[0];
  const int*   cat_id   = (const int*)  d_in[1];
  const int*   src_in   = (const int*)  d_in[2];
  const int*   dst_in   = (const int*)  d_in[3];
  const float* emb_item = (const float*)d_in[4];
  const float* emb_cat  = (const float*)d_in[5];
  const float* W1r = (const float*)d_in[6];
  const float* W1n = (const float*)d_in[7];
  const float* b1  = (const float*)d_in[8];
  const float* p1  = (const float*)d_in[9];
  const float* W2r = (const float*)d_in[10];
  const float* W2n = (const float*)d_in[11];
  const float* b2  = (const float*)d_in[12];
  const float* p2  = (const float*)d_in[13];
  const float* W3r = (const float*)d_in[14];
  const float* W3n = (const float*)d_in[15];
  const float* b3  = (const float*)d_in[16];
  const float* p3  = (const float*)d_in[17];
  const float* fc1_W = (const float*)d_in[18];
  const float* fc1_b = (const float*)d_in[19];
  const float* bn1_g = (const float*)d_in[20];
  const float* bn1_b = (const float*)d_in[21];
  const float* fc2_W = (const float*)d_in[22];
  const float* fc2_b = (const float*)d_in[23];
  const float* bn2_g = (const float*)d_in[24];
  const float* bn2_b = (const float*)d_in[25];
  float* out = (float*)d_out;

  const int TN = TOTAL_NODES;
  const int E  = E_TOTAL;
  const int k1 = 461, k2 = 415, k3 = 374;
  const int M1 = TN;              // 131072
  const int M2 = NUM_GRAPHS * k1; // 118016
  const int M3 = NUM_GRAPHS * k2; // 106240

  char* ws = (char*)d_ws;
  size_t off = 0;
  auto carve = [&](size_t bytes) { char* p = ws + off; off += align256(bytes); return p; };
  float*  buf0   = (float*) carve((size_t)TN * FDIM * 4);
  float*  buf1   = (float*) carve((size_t)TN * FDIM * 4);
  float*  score  = (float*) carve((size_t)TN * 4);
  int*    sel    = (int*)   carve((size_t)TN * 4);
  int*    mapping= (int*)   carve((size_t)TN * 4);
  float*  gates  = (float*) carve((size_t)TN * 4);
  int*    srcw   = (int*)   carve((size_t)E * 4);
  int*    dstw   = (int*)   carve((size_t)E * 4);
  int*    counts = (int*)   carve((size_t)TN * 4);
  int*    offs   = (int*)   carve((size_t)TN * 4);
  int2*   slotp  = (int2*)  carve((size_t)E * 8);
  __bf16* wbuf   = (__bf16*)carve(6 * 2 * 16384 * 2);
  float*  g      = (float*) carve(256 * 256 * 4);
  float*  h1     = (float*) carve(256 * 128 * 4);
  float*  h2     = (float*) carve(256 * 64 * 4);
  float*  nrm    = (float*) carve(256);
  if (off > ws_size) return;

  dim3 b256(256);
  auto blocks = [](long long work, int bs) { return dim3((unsigned)((work + bs - 1) / bs)); };

  const __bf16* W1r_hl = wbuf + 0 * 2 * 16384;
  const __bf16* W1n_hl = wbuf + 1 * 2 * 16384;
  const __bf16* W2r_hl = wbuf + 2 * 2 * 16384;
  const __bf16* W2n_hl = wbuf + 3 * 2 * 16384;
  const __bf16* W3r_hl = wbuf + 4 * 2 * 16384;
  const __bf16* W3n_hl = wbuf + 5 * 2 * 16384;

  hipMemsetAsync(g, 0, 256 * 256 * 4, stream);
  wprep_k<<<dim3(64, 6), b256, 0, stream>>>(W1r, W1n, W2r, W2n, W3r, W3n, wbuf);
  pnorm3_k<<<dim3(1), dim3(128), 0, stream>>>(p1, p2, p3, nrm);
  gather_embed_k<<<blocks((long long)TN * 32, 256), b256, 0, stream>>>(
      item_id, cat_id, emb_item, emb_cat, buf0, TN);

  // ================= stage 1 (x0 = buf0, dense) =================
  csr_build_k<<<dim3(NUM_GRAPHS), dim3(512), 0, stream>>>(
      src_in, dst_in, nullptr, nullptr, nullptr,
      srcw, dstw, slotp, counts, offs, NODES_PER_G);
  gather_direct_k<<<blocks((long long)M1 * 32, 256), b256, 0, stream>>>(
      buf0, slotp, offs, counts, buf1, M1);
  conv_mfma_k<<<dim3(M1 / 128), b256, 0, stream>>>(
      buf0, nullptr, nullptr, W1r_hl, buf1, W1n_hl, b1, p1, nrm + 0, buf0, score, M1);
  topk_sort_k<<<dim3(NUM_GRAPHS), dim3(512), 0, stream>>>(
      score, NODES_PER_G, k1, sel, mapping, gates);
  readout_k<<<dim3(NUM_GRAPHS, 4), b256, 0, stream>>>(buf0, sel, gates, g, k1);

  // ================= stage 2 (x1 = buf0 via sel/gates) =================
  csr_build_k<<<dim3(NUM_GRAPHS), dim3(512), 0, stream>>>(
      srcw, dstw, mapping, sel, gates,
      srcw, dstw, slotp, counts, offs, k1);
  gather_direct_k<<<blocks((long long)M2 * 32, 256), b256, 0, stream>>>(
      buf0, slotp, offs, counts, buf1, M2);
  conv_mfma_k<<<dim3(M2 / 128), b256, 0, stream>>>(
      buf0, sel, gates, W2r_hl, buf1, W2n_hl, b2, p2, nrm + 1, buf1, score, M2);
  topk_sort_k<<<dim3(NUM_GRAPHS), dim3(512), 0, stream>>>(
      score, k1, k2, sel, mapping, gates);
  readout_k<<<dim3(NUM_GRAPHS, 4), b256, 0, stream>>>(buf1, sel, gates, g, k2);

  // ================= stage 3 (x2 = buf1 via sel/gates) =================
  csr_build_k<<<dim3(NUM_GRAPHS), dim3(512), 0, stream>>>(
      srcw, dstw, mapping, sel, gates,
      srcw, dstw, slotp, counts, offs, k2);
  gather_direct_k<<<blocks((long long)M3 * 32, 256), b256, 0, stream>>>(
      buf1, slotp, offs, counts, buf0, M3);
  conv_mfma_k<<<dim3(M3 / 128), b256, 0, stream>>>(
      buf1, sel, gates, W3r_hl, buf0, W3n_hl, b3, p3, nrm + 2, buf0, score, M3);
  topk_sort_k<<<dim3(NUM_GRAPHS), dim3(512), 0, stream>>>(
      score, k2, k3, sel, mapping, gates);
  readout_k<<<dim3(NUM_GRAPHS, 4), b256, 0, stream>>>(buf0, sel, gates, g, k3);

  // ================= head (fused fc+bn+relu) =================
  head1_k<<<dim3(16), b256, 0, stream>>>(g, fc1_W, fc1_b, bn1_g, bn1_b, h1);
  head2_k<<<dim3(8), b256, 0, stream>>>(h1, fc2_W, fc2_b, bn2_g, bn2_b, h2);

  final_k<<<blocks(TN, 256), b256, 0, stream>>>(item_id, emb_item, h2, out, TN);
}